// Round 3
// baseline (736.472 us; speedup 1.0000x reference)
//
#include <hip/hip_runtime.h>
#include <hip/hip_fp16.h>
#include <math.h>

#define BB 2
#define CC 64
#define NN 4096
#define MM 256
#define KK 32
#define GG 4
#define EPSF 1e-5f

__device__ __forceinline__ float gelu_exact(float x) {
    return 0.5f * x * (1.0f + erff(x * 0.70710678118654752f));
}

__device__ __forceinline__ unsigned pkmax(unsigned a, unsigned b) {
    unsigned d;
    asm("v_pk_max_f16 %0, %1, %2" : "=v"(d) : "v"(a), "v"(b));
    return d;
}
__device__ __forceinline__ unsigned pkmin(unsigned a, unsigned b) {
    unsigned d;
    asm("v_pk_min_f16 %0, %1, %2" : "=v"(d) : "v"(a), "v"(b));
    return d;
}
__device__ __forceinline__ unsigned selpair(unsigned mx, unsigned mn, float g0, float g1) {
    unsigned lo = (g0 >= 0.f) ? (mx & 0x0000FFFFu) : (mn & 0x0000FFFFu);
    unsigned hi = (g1 >= 0.f) ? (mx & 0xFFFF0000u) : (mn & 0xFFFF0000u);
    return lo | hi;
}
__device__ __forceinline__ float bcast_lane(float v, int lane) {
    return __int_as_float(__builtin_amdgcn_readlane(__float_as_int(v), lane));
}

// Manual grid barrier. Correct only because all 512 blocks are co-resident BY
// CONSTRUCTION: LDS 74240B -> exactly 2 blocks/CU (148.5KB <= 160KB),
// launch_bounds(256,2) -> VGPR<=256 -> 8 waves/CU fit, grid 512 = 2 x 256 CUs.
// bar: 4 counters spaced 64B apart, zeroed by hipMemsetAsync before launch.
// Release: thread-0 __threadfence() (L2 writeback, cross-XCD visibility) before
// the device-scope atomicAdd; acquire: poll with __hip_atomic_load(ACQUIRE,AGENT)
// then all-thread __threadfence() after __syncthreads (L1/L2 invalidate).
__device__ __forceinline__ void gridbar(unsigned* bar, int which, int t, unsigned nblk) {
    __syncthreads();
    if (t == 0) {
        unsigned* c = bar + which * 16;
        __threadfence();
        atomicAdd(c, 1u);
        while (__hip_atomic_load(c, __ATOMIC_ACQUIRE, __HIP_MEMORY_SCOPE_AGENT) < nblk) {
            __builtin_amdgcn_s_sleep(2);
        }
    }
    __syncthreads();
    __threadfence();
}

// Shared-memory union (max over phases = phase-4 mlp2g: 65792 + 8192 + 128 + 64 + 64)
#define SM_BYTES 74240

// ---------------- mega: all 5 phases, grid 512 x 256, manual grid barrier ----------------
// All phase bodies are arithmetically identical to the 145us 5-kernel version:
//   phase 1 = k_mlp1        (512 block-units, 1:1)
//   phase 2 = gn1t (1:1) then ballq (4 sequential queries per wave; per-query
//             distance expression tree byte-identical -- fma-contraction safe)
//   phase 3 = k_gstats      (blocks 0..255, body unchanged)
//   phase 4 = k_mlp2g       (1:1)
//   phase 5 = k_final       (1:1)
__global__ __launch_bounds__(256, 2)
void k_mega(const float* __restrict__ x, const float* __restrict__ pos,
            const float* __restrict__ w1, const float* __restrict__ b1,
            const float* __restrict__ g1, const float* __restrict__ be1,
            const float* __restrict__ wd, const float* __restrict__ gd,
            const float* __restrict__ bed, const float* __restrict__ w2,
            const float* __restrict__ b2, const float* __restrict__ g2,
            const float* __restrict__ be2, float* __restrict__ out,
            __half* __restrict__ hH, __half* __restrict__ pH,
            float* __restrict__ oraw, int* __restrict__ idxb,
            float* __restrict__ R, float2* __restrict__ Mp,
            float* __restrict__ Gp, float* __restrict__ Op,
            unsigned* __restrict__ bar) {
    __shared__ __align__(16) char smraw[SM_BYTES];
    int t = threadIdx.x;
    int bx = blockIdx.x;

    // ================= phase 1: mlp1 =================
    {
        float* xs  = (float*)smraw;          // 64*128
        float* w1t = xs + 64 * 128;          // 64*32
        float* r1  = w1t + 64 * 32;          // 4
        float* r2  = r1 + 4;                 // 4

        int nt = bx & 31, mt = (bx >> 5) & 7, b = bx >> 8;
        int n0 = nt * 128, m0 = mt * 32;

        {
            int nq = t & 31, ch = t >> 5;
            #pragma unroll
            for (int p = 0; p < 8; p++) {
                int c = p * 8 + ch;
                float4 v = *(const float4*)&x[((size_t)(b * CC + c)) * NN + n0 + nq * 4];
                *(float4*)&xs[c * 128 + nq * 4] = v;
            }
        }
        {
            #pragma unroll
            for (int p = 0; p < 2; p++) {
                int idx = p * 256 + t;
                int m = idx >> 4, cq = idx & 15;
                float4 v = *(const float4*)&w1[(m0 + m) * CC + cq * 4];
                w1t[(cq * 4 + 0) * 32 + m] = v.x;
                w1t[(cq * 4 + 1) * 32 + m] = v.y;
                w1t[(cq * 4 + 2) * 32 + m] = v.z;
                w1t[(cq * 4 + 3) * 32 + m] = v.w;
            }
        }
        __syncthreads();

        int nq = t & 31;
        int mseg = t >> 5;
        float o[4][4];
        #pragma unroll
        for (int i = 0; i < 4; i++)
            #pragma unroll
            for (int j = 0; j < 4; j++) o[i][j] = 0.f;

        for (int c = 0; c < 64; c++) {
            float4 xv = *(float4*)&xs[c * 128 + nq * 4];
            float4 wv = *(float4*)&w1t[c * 32 + mseg * 4];
            o[0][0] = fmaf(wv.x, xv.x, o[0][0]); o[0][1] = fmaf(wv.x, xv.y, o[0][1]);
            o[0][2] = fmaf(wv.x, xv.z, o[0][2]); o[0][3] = fmaf(wv.x, xv.w, o[0][3]);
            o[1][0] = fmaf(wv.y, xv.x, o[1][0]); o[1][1] = fmaf(wv.y, xv.y, o[1][1]);
            o[1][2] = fmaf(wv.y, xv.z, o[1][2]); o[1][3] = fmaf(wv.y, xv.w, o[1][3]);
            o[2][0] = fmaf(wv.z, xv.x, o[2][0]); o[2][1] = fmaf(wv.z, xv.y, o[2][1]);
            o[2][2] = fmaf(wv.z, xv.z, o[2][2]); o[2][3] = fmaf(wv.z, xv.w, o[2][3]);
            o[3][0] = fmaf(wv.w, xv.x, o[3][0]); o[3][1] = fmaf(wv.w, xv.y, o[3][1]);
            o[3][2] = fmaf(wv.w, xv.z, o[3][2]); o[3][3] = fmaf(wv.w, xv.w, o[3][3]);
        }

        float s1 = 0.f, s2 = 0.f;
        #pragma unroll
        for (int mi = 0; mi < 4; mi++) {
            int m = m0 + mseg * 4 + mi;
            float bv = b1[m];
            float4 r;
            r.x = o[mi][0] + bv; r.y = o[mi][1] + bv;
            r.z = o[mi][2] + bv; r.w = o[mi][3] + bv;
            __half2 hA = __float22half2_rn(make_float2(r.x, r.y));
            __half2 hB = __float22half2_rn(make_float2(r.z, r.w));
            uint2 st8;
            st8.x = *(unsigned*)&hA; st8.y = *(unsigned*)&hB;
            *(uint2*)((char*)hH + (((size_t)(b * MM + m)) * NN + n0 + nq * 4) * 2) = st8;
            s1 += r.x + r.y + r.z + r.w;
            s2 = fmaf(r.x, r.x, s2); s2 = fmaf(r.y, r.y, s2);
            s2 = fmaf(r.z, r.z, s2); s2 = fmaf(r.w, r.w, s2);
        }
        for (int off = 32; off; off >>= 1) {
            s1 += __shfl_down(s1, off, 64);
            s2 += __shfl_down(s2, off, 64);
        }
        int w = t >> 6, l = t & 63;
        if (l == 0) { r1[w] = s1; r2[w] = s2; }
        __syncthreads();
        if (t == 0) {
            Mp[bx] = make_float2(r1[0] + r1[1] + r1[2] + r1[3],
                                 r2[0] + r2[1] + r2[2] + r2[3]);
        }
    }
    gridbar(bar, 0, t, 512u);

    // ================= phase 2a: gn1t =================
    {
        float* tile = (float*)smraw;         // 64*65
        float* mv   = tile + 64 * 65;        // 2

        int id = bx;
        int n0 = (id & 63) * 64;
        int g  = (id >> 6) & 3;
        int b  = id >> 8;
        int m0 = g * 64;

        if (t < 64) {
            float2 p2 = Mp[b * 256 + g * 64 + t];
            float s1 = p2.x, s2 = p2.y;
            for (int off = 32; off; off >>= 1) {
                s1 += __shfl_down(s1, off, 64);
                s2 += __shfl_down(s2, off, 64);
            }
            if (t == 0) {
                const double cnt = 64.0 * 4096.0;
                double md = (double)s1 / cnt;
                double vd = (double)s2 / cnt - md * md;
                mv[0] = (float)md;
                mv[1] = rsqrtf((float)vd + EPSF);
            }
        }
        __syncthreads();
        float mean = mv[0], rstd = mv[1];

        int nq = t & 15, mr = t >> 4;
        #pragma unroll
        for (int pp = 0; pp < 4; pp++) {
            int row = pp * 16 + mr;
            int m = m0 + row;
            float a = rstd * g1[m];
            float cc2 = be1[m] - mean * a;
            float wdm = wd[m];
            uint2 raw = *(const uint2*)((const char*)hH +
                         (((size_t)(b * MM + m)) * NN + n0 + nq * 4) * 2);
            float2 fa = __half22float2(*(__half2*)&raw.x);
            float2 fb = __half22float2(*(__half2*)&raw.y);
            tile[row * 65 + nq * 4 + 0] = gelu_exact(fmaf(fa.x, a, cc2)) * wdm;
            tile[row * 65 + nq * 4 + 1] = gelu_exact(fmaf(fa.y, a, cc2)) * wdm;
            tile[row * 65 + nq * 4 + 2] = gelu_exact(fmaf(fb.x, a, cc2)) * wdm;
            tile[row * 65 + nq * 4 + 3] = gelu_exact(fmaf(fb.y, a, cc2)) * wdm;
        }
        __syncthreads();
        #pragma unroll
        for (int pp = 0; pp < 4; pp++) {
            int id2 = pp * 256 + t;
            int nl = id2 >> 4, mq = id2 & 15;
            float a0 = tile[(mq * 4 + 0) * 65 + nl];
            float a1 = tile[(mq * 4 + 1) * 65 + nl];
            float a2 = tile[(mq * 4 + 2) * 65 + nl];
            float a3 = tile[(mq * 4 + 3) * 65 + nl];
            __half2 hA = __float22half2_rn(make_float2(a0, a1));
            __half2 hB = __float22half2_rn(make_float2(a2, a3));
            uint2 st8;
            st8.x = *(unsigned*)&hA; st8.y = *(unsigned*)&hB;
            *(uint2*)((char*)pH + ((((size_t)(b * NN) + n0 + nl)) << 9) + (m0 + mq * 4) * 2) = st8;
            float2 fa = __half22float2(hA);
            float2 fb = __half22float2(hB);
            float t1 = fa.x + fa.y + fb.x + fb.y;
            float t2 = fa.x * fa.x + fa.y * fa.y + fb.x * fb.x + fb.y * fb.y;
            #pragma unroll
            for (int off = 8; off; off >>= 1) {
                t1 += __shfl_down(t1, off, 16);
                t2 += __shfl_down(t2, off, 16);
            }
            if ((t & 15) == 0) {
                float* rr = &R[((size_t)(b * NN) + n0 + nl) * 8];
                rr[g]     = t1;
                rr[4 + g] = t2;
            }
        }
    }

    // ================= phase 2b: ballq (4 sequential queries per wave) =================
    {
        int wv = t >> 6;
        int lane = t & 63;
        #pragma unroll 1
        for (int qi = 0; qi < 4; qi++) {
            int wid = (bx * 4 + wv) * 4 + qi;     // [0, 8192)
            int b = wid >> 12;
            int n = wid & 4095;
            const float* px = pos + b * 3 * NN;
            const float* py = px + NN;
            const float* pz = py + NN;
            float qx = px[n], qy = py[n], qz = pz[n];
            float qsq = qx*qx + qy*qy + qz*qz;
            int* row = idxb + (b * NN + n) * KK;

            int found = 0;
            int first = -1;
            const float R2 = 0.04f;
            for (int m0 = 0; m0 < NN && found < KK; m0 += 64) {
                int m = m0 + lane;
                float ax = px[m], ay = py[m], az = pz[m];
                float msq = ax*ax + ay*ay + az*az;
                float dot = qx*ax + qy*ay + qz*az;
                float d = qsq + msq - 2.0f * dot;
                bool hit = !(d > R2);
                unsigned long long mask = __ballot(hit);
                if (first < 0 && mask) first = m0 + (__ffsll((long long)mask) - 1);
                unsigned long long lt = (lane == 0) ? 0ULL : (mask & ((1ULL << lane) - 1ULL));
                int posh = __popcll(lt);
                if (hit && (found + posh) < KK) row[found + posh] = m;
                found += __popcll(mask);
                if (found > KK) found = KK;
            }
            if (lane < KK && lane >= found) row[lane] = first;
        }
    }
    gridbar(bar, 1, t, 512u);

    // ================= phase 3: gstats (blocks 0..255, body unchanged) =================
    if (bx < 256) {
        float (*sAcc)[8] = (float(*)[8])smraw;
        int bid = bx;
        int hw = t >> 5, cl = t & 31;
        int pbase = bid * 32;
        int b = pbase >> 12;
        float s[8];
        #pragma unroll
        for (int c = 0; c < 8; c++) s[c] = 0.f;
        #pragma unroll
        for (int it = 0; it < 4; it++) {
            int pt = pbase + it * 8 + hw;
            int j = idxb[pt * KK + cl];
            const float* rr = &R[((size_t)(b * NN) + j) * 8];
            float4 ra = *(const float4*)rr;
            float4 rb = *(const float4*)(rr + 4);
            s[0] += ra.x; s[1] += ra.y; s[2] += ra.z; s[3] += ra.w;
            s[4] += rb.x; s[5] += rb.y; s[6] += rb.z; s[7] += rb.w;
        }
        #pragma unroll
        for (int off = 16; off; off >>= 1) {
            #pragma unroll
            for (int c = 0; c < 8; c++) s[c] += __shfl_down(s[c], off, 32);
        }
        if (cl == 0) {
            #pragma unroll
            for (int c = 0; c < 8; c++) sAcc[hw][c] = s[c];
        }
        __syncthreads();
        if (t < 8) {
            float v = 0.f;
            #pragma unroll
            for (int k = 0; k < 8; k++) v += sAcc[k][t];
            Gp[bid * 8 + t] = v;
        }
    }
    gridbar(bar, 2, t, 512u);

    // ================= phase 4: mlp2g =================
    {
        float* w2s  = (float*)smraw;                               // 64*257 floats
        uint4* phs4 = (uint4*)(smraw + 64 * 257 * 4);              // [4][4][32] uint4
        float (*sw)[8] = (float(*)[8])(smraw + 64 * 257 * 4 + 8192);
        float (*sA)[4] = (float(*)[4])(smraw + 64 * 257 * 4 + 8192 + 128);
        float (*sB)[4] = (float(*)[4])(smraw + 64 * 257 * 4 + 8192 + 128 + 64);

        int w = t >> 6, l = t & 63;
        int q = bx;
        int b = ((q & 7) < 4) ? 0 : 1;
        int local = (q >> 3) * 4 + (q & 3);        // [0, 256), unique per batch
        int n0 = local * 16 + w * 4;

        #pragma unroll
        for (int p = 0; p < 16; p++) {
            int i = p * 256 + t;
            int c = i >> 6, mq = i & 63;
            float4 v = ((const float4*)w2)[i];
            float* dst = &w2s[c * 257 + mq * 4];
            dst[0] = v.x; dst[1] = v.y; dst[2] = v.z; dst[3] = v.w;
        }

        {
            float s[8] = {0.f, 0.f, 0.f, 0.f, 0.f, 0.f, 0.f, 0.f};
            if (t < 128) {
                const float4* gp = (const float4*)(Gp + ((size_t)(b * 128 + t)) * 8);
                float4 ra = gp[0], rb = gp[1];
                s[0] = ra.x; s[1] = ra.y; s[2] = ra.z; s[3] = ra.w;
                s[4] = rb.x; s[5] = rb.y; s[6] = rb.z; s[7] = rb.w;
            }
            #pragma unroll
            for (int off = 32; off; off >>= 1) {
                #pragma unroll
                for (int c = 0; c < 8; c++) s[c] += __shfl_down(s[c], off, 64);
            }
            if (l == 0) {
                #pragma unroll
                for (int c = 0; c < 8; c++) sw[w][c] = s[c];
            }
        }
        __syncthreads();

        int g = l >> 4;
        double s1 = (double)sw[0][g] + sw[1][g] + sw[2][g] + sw[3][g];
        double s2 = (double)sw[0][4 + g] + sw[1][4 + g] + sw[2][4 + g] + sw[3][4 + g];
        const double cnt2 = 64.0 * 4096.0 * 32.0;
        double m_ = s1 / cnt2;
        double v_ = s2 / cnt2 - m_ * m_;
        float mean = (float)m_;
        float rstd = rsqrtf((float)v_ + EPSF);
        float4 gd4  = ((const float4*)gd)[l];
        float4 bed4 = ((const float4*)bed)[l];
        float ax = rstd * gd4.x, ay = rstd * gd4.y, az = rstd * gd4.z, aw = rstd * gd4.w;
        float cx = bed4.x - mean * ax, cy = bed4.y - mean * ay;
        float cz = bed4.z - mean * az, cw = bed4.w - mean * aw;

        // ---- fused gather for this wave's 4 columns ----
        {
            int hh = l >> 5, cl = l & 31;
            const char* pb = (const char*)(pH + (size_t)b * NN * 256);
            int laneoff = cl * 16;
            const float4* g4 = (const float4*)gd;
            float4 gA = g4[cl * 2], gB = g4[cl * 2 + 1];
            #pragma unroll
            for (int p = 0; p < 4; p++) {
                int myidx = idxb[((size_t)(b * NN) + n0 + p) * KK + cl];
                unsigned vmax0 = 0xFC00FC00u, vmax1 = 0xFC00FC00u, vmax2 = 0xFC00FC00u, vmax3 = 0xFC00FC00u;
                unsigned vmin0 = 0x7C007C00u, vmin1 = 0x7C007C00u, vmin2 = 0x7C007C00u, vmin3 = 0x7C007C00u;
                #pragma unroll
                for (int kb = 0; kb < 4; kb++) {
                    int jj[4];
                    #pragma unroll
                    for (int u = 0; u < 4; u++) {
                        int k = kb * 4 + u;
                        int ja = __shfl(myidx, 2 * k, 64);
                        int jb = __shfl(myidx, 2 * k + 1, 64);
                        jj[u] = hh ? jb : ja;
                    }
                    uint4 r[4];
                    #pragma unroll
                    for (int u = 0; u < 4; u++)
                        r[u] = *(const uint4*)(pb + (((size_t)jj[u]) << 9) + laneoff);
                    #pragma unroll
                    for (int u = 0; u < 4; u++) {
                        vmax0 = pkmax(vmax0, r[u].x); vmin0 = pkmin(vmin0, r[u].x);
                        vmax1 = pkmax(vmax1, r[u].y); vmin1 = pkmin(vmin1, r[u].y);
                        vmax2 = pkmax(vmax2, r[u].z); vmin2 = pkmin(vmin2, r[u].z);
                        vmax3 = pkmax(vmax3, r[u].w); vmin3 = pkmin(vmin3, r[u].w);
                    }
                }
                vmax0 = pkmax(vmax0, (unsigned)__shfl_xor((int)vmax0, 32, 64));
                vmax1 = pkmax(vmax1, (unsigned)__shfl_xor((int)vmax1, 32, 64));
                vmax2 = pkmax(vmax2, (unsigned)__shfl_xor((int)vmax2, 32, 64));
                vmax3 = pkmax(vmax3, (unsigned)__shfl_xor((int)vmax3, 32, 64));
                vmin0 = pkmin(vmin0, (unsigned)__shfl_xor((int)vmin0, 32, 64));
                vmin1 = pkmin(vmin1, (unsigned)__shfl_xor((int)vmin1, 32, 64));
                vmin2 = pkmin(vmin2, (unsigned)__shfl_xor((int)vmin2, 32, 64));
                vmin3 = pkmin(vmin3, (unsigned)__shfl_xor((int)vmin3, 32, 64));

                if (hh == 0) {
                    uint4 o4;
                    o4.x = selpair(vmax0, vmin0, gA.x, gA.y);
                    o4.y = selpair(vmax1, vmin1, gA.z, gA.w);
                    o4.z = selpair(vmax2, vmin2, gB.x, gB.y);
                    o4.w = selpair(vmax3, vmin3, gB.z, gB.w);
                    phs4[(w * 4 + p) * 32 + cl] = o4;   // per-wave slot: same-wave RAW
                }
            }
        }

        // ---- GN + gelu on the gathered columns ----
        float4 h2r[4];
        #pragma unroll
        for (int j = 0; j < 4; j++) {
            const uint2* pr = (const uint2*)(phs4 + (w * 4 + j) * 32);
            uint2 raw = pr[l];
            float2 fa = __half22float2(*(__half2*)&raw.x);
            float2 fb = __half22float2(*(__half2*)&raw.y);
            h2r[j].x = gelu_exact(fmaf(fa.x, ax, cx));
            h2r[j].y = gelu_exact(fmaf(fa.y, ay, cy));
            h2r[j].z = gelu_exact(fmaf(fb.x, az, cz));
            h2r[j].w = gelu_exact(fmaf(fb.y, aw, cw));
        }

        const float* w2l = &w2s[l * 257];
        float acc[4] = {0.f, 0.f, 0.f, 0.f};
        #pragma unroll 8
        for (int mq = 0; mq < 64; mq++) {
            float w0  = w2l[4 * mq + 0];
            float w1_ = w2l[4 * mq + 1];
            float w2_ = w2l[4 * mq + 2];
            float w3_ = w2l[4 * mq + 3];
            #pragma unroll
            for (int j = 0; j < 4; j++) {
                acc[j] = fmaf(w0,  bcast_lane(h2r[j].x, mq), acc[j]);
                acc[j] = fmaf(w1_, bcast_lane(h2r[j].y, mq), acc[j]);
                acc[j] = fmaf(w2_, bcast_lane(h2r[j].z, mq), acc[j]);
                acc[j] = fmaf(w3_, bcast_lane(h2r[j].w, mq), acc[j]);
            }
        }

        float bias = b2[l];
        float so1 = 0.f, so2 = 0.f;
        #pragma unroll
        for (int j = 0; j < 4; j++) {
            acc[j] += bias;
            so1 += acc[j];
            so2 = fmaf(acc[j], acc[j], so2);
        }
        *(float4*)&oraw[((size_t)(b * CC) + l) * NN + n0] =
            make_float4(acc[0], acc[1], acc[2], acc[3]);

        so1 += __shfl_down(so1, 8, 16); so2 += __shfl_down(so2, 8, 16);
        so1 += __shfl_down(so1, 4, 16); so2 += __shfl_down(so2, 4, 16);
        so1 += __shfl_down(so1, 2, 16); so2 += __shfl_down(so2, 2, 16);
        so1 += __shfl_down(so1, 1, 16); so2 += __shfl_down(so2, 1, 16);
        if ((l & 15) == 0) { sA[w][l >> 4] = so1; sB[w][l >> 4] = so2; }
        __syncthreads();
        if (t < 8) {
            int is2 = t >> 2, gg = t & 3;
            float v = is2 ? (sB[0][gg] + sB[1][gg] + sB[2][gg] + sB[3][gg])
                          : (sA[0][gg] + sA[1][gg] + sA[2][gg] + sA[3][gg]);
            Op[(b * 256 + local) * 8 + t] = v;
        }
    }
    gridbar(bar, 3, t, 512u);

    // ================= phase 5: final =================
    {
        float (*fw)[8] = (float(*)[8])smraw;
        int i4 = bx * 256 + t;
        int base = i4 * 4;
        int b = base >> 18;

        {
            const float4* rp = (const float4*)(Op + ((size_t)(b * 256 + t)) * 8);
            float4 ra = rp[0], rb = rp[1];
            float s[8] = {ra.x, ra.y, ra.z, ra.w, rb.x, rb.y, rb.z, rb.w};
            #pragma unroll
            for (int off = 32; off; off >>= 1) {
                #pragma unroll
                for (int c = 0; c < 8; c++) s[c] += __shfl_down(s[c], off, 64);
            }
            if ((t & 63) == 0) {
                #pragma unroll
                for (int c = 0; c < 8; c++) fw[t >> 6][c] = s[c];
            }
        }
        __syncthreads();

        int c = (base >> 12) & 63;
        int g = c >> 4;
        double s1 = (double)fw[0][g] + fw[1][g] + fw[2][g] + fw[3][g];
        double s2 = (double)fw[0][4 + g] + fw[1][4 + g] + fw[2][4 + g] + fw[3][4 + g];
        const double cnt = 16.0 * 4096.0;
        double mean_d = s1 / cnt;
        double var_d  = s2 / cnt - mean_d * mean_d;
        float mean = (float)mean_d;
        float rstd = rsqrtf((float)var_d + EPSF);
        float sc = rstd * g2[c];
        float ad = be2[c] - mean * sc;
        float4 o = ((const float4*)oraw)[i4];
        float4 xv = ((const float4*)x)[i4];
        float4 r;
        r.x = fmaf(o.x, sc, ad) + xv.x;
        r.y = fmaf(o.y, sc, ad) + xv.y;
        r.z = fmaf(o.z, sc, ad) + xv.z;
        r.w = fmaf(o.w, sc, ad) + xv.w;
        ((float4*)out)[i4] = r;
    }
}

// ---------------- launch ----------------
extern "C" void kernel_launch(void* const* d_in, const int* in_sizes, int n_in,
                              void* d_out, int out_size, void* d_ws, size_t ws_size,
                              hipStream_t stream) {
    const float* x   = (const float*)d_in[0];
    const float* pos = (const float*)d_in[1];
    const float* w1  = (const float*)d_in[2];
    const float* b1  = (const float*)d_in[3];
    const float* g1  = (const float*)d_in[4];
    const float* be1 = (const float*)d_in[5];
    const float* wd  = (const float*)d_in[6];
    const float* gd  = (const float*)d_in[7];
    const float* bed = (const float*)d_in[8];
    const float* w2  = (const float*)d_in[9];
    const float* b2  = (const float*)d_in[10];
    const float* g2  = (const float*)d_in[11];
    const float* be2 = (const float*)d_in[12];
    float* out = (float*)d_out;

    char* wsb = (char*)d_ws;
    __half* hH    = (__half*)wsb;                    // 4 MB (fp16 h)
    __half* pH    = (__half*)(wsb + 8388608);        // 4 MB
    float*  oraw  = (float*)(wsb + 16777216);        // 2 MB
    int*    idxb  = (int*)(wsb + 18874368);          // 1 MB
    float*  R     = (float*)(wsb + 19922944);        // 256 KB
    float2* Mp    = (float2*)(wsb + 20185088);       // 4 KB
    float*  Gp    = (float*)(wsb + 20189184);        // 8 KB
    float*  Op    = (float*)(wsb + 20197376);        // 16 KB
    unsigned* bar = (unsigned*)(wsb + 20213760);     // 256 B (4 counters, 64B apart)

    hipMemsetAsync((void*)bar, 0, 256, stream);
    k_mega<<<512, 256, 0, stream>>>(x, pos, w1, b1, g1, be1, wd, gd, bed,
                                    w2, b2, g2, be2, out,
                                    hH, pH, oraw, idxb, R, Mp, Gp, Op, bar);
}

// Round 4
// 214.478 us; speedup vs baseline: 3.4338x; 3.4338x over previous
//
#include <hip/hip_runtime.h>
#include <hip/hip_fp16.h>
#include <math.h>

#define BB 2
#define CC 64
#define NN 4096
#define MM 256
#define KK 32
#define GG 4
#define EPSF 1e-5f

__device__ __forceinline__ float gelu_exact(float x) {
    return 0.5f * x * (1.0f + erff(x * 0.70710678118654752f));
}

__device__ __forceinline__ unsigned pkmax(unsigned a, unsigned b) {
    unsigned d;
    asm("v_pk_max_f16 %0, %1, %2" : "=v"(d) : "v"(a), "v"(b));
    return d;
}
__device__ __forceinline__ unsigned pkmin(unsigned a, unsigned b) {
    unsigned d;
    asm("v_pk_min_f16 %0, %1, %2" : "=v"(d) : "v"(a), "v"(b));
    return d;
}
__device__ __forceinline__ unsigned selpair(unsigned mx, unsigned mn, float g0, float g1) {
    unsigned lo = (g0 >= 0.f) ? (mx & 0x0000FFFFu) : (mn & 0x0000FFFFu);
    unsigned hi = (g1 >= 0.f) ? (mx & 0xFFFF0000u) : (mn & 0xFFFF0000u);
    return lo | hi;
}
__device__ __forceinline__ float bcast_lane(float v, int lane) {
    return __int_as_float(__builtin_amdgcn_readlane(__float_as_int(v), lane));
}

// ---------------- kernel A: mlp1 (blocks 0..511) UNION ballq+cnt (512..2559) ----------
// ballq is independent of mlp1, so it moves into kernel 1 (it must now PRECEDE gn1t,
// because gn1t consumes the cnt histogram). cnt[j] counts occurrences of column j in
// the final idx table (accepted hits + the (32-found) duplicated `first` fills) --
// this is what lets GN2 stats collapse to sum_j cnt[j]*R[j] inside gn1t.
// mlp1 LDS trimmed to exactly 40KB (r1/r2 aliased onto dead w1t after a barrier)
// so union occupancy stays 4 blocks/CU.
__global__ void k_mlp1_ballq(const float* __restrict__ x, const float* __restrict__ w1,
                             const float* __restrict__ b1, __half* __restrict__ hH,
                             float2* __restrict__ Mp,
                             const float* __restrict__ pos, int* __restrict__ idxb,
                             int* __restrict__ cnt) {
    __shared__ __align__(16) float xs[64 * 128];
    __shared__ __align__(16) float w1t[64 * 32];
    int t = threadIdx.x;

    if (blockIdx.x < 512) {
        // ---- mlp1 body (identical arithmetic to the 145us version) ----
        int bx = blockIdx.x;
        int nt = bx & 31, mt = (bx >> 5) & 7, b = bx >> 8;
        int n0 = nt * 128, m0 = mt * 32;

        {
            int nq = t & 31, ch = t >> 5;
            #pragma unroll
            for (int p = 0; p < 8; p++) {
                int c = p * 8 + ch;
                float4 v = *(const float4*)&x[((size_t)(b * CC + c)) * NN + n0 + nq * 4];
                *(float4*)&xs[c * 128 + nq * 4] = v;
            }
        }
        {
            #pragma unroll
            for (int p = 0; p < 2; p++) {
                int idx = p * 256 + t;
                int m = idx >> 4, cq = idx & 15;
                float4 v = *(const float4*)&w1[(m0 + m) * CC + cq * 4];
                w1t[(cq * 4 + 0) * 32 + m] = v.x;
                w1t[(cq * 4 + 1) * 32 + m] = v.y;
                w1t[(cq * 4 + 2) * 32 + m] = v.z;
                w1t[(cq * 4 + 3) * 32 + m] = v.w;
            }
        }
        __syncthreads();

        int nq = t & 31;
        int mseg = t >> 5;
        float o[4][4];
        #pragma unroll
        for (int i = 0; i < 4; i++)
            #pragma unroll
            for (int j = 0; j < 4; j++) o[i][j] = 0.f;

        for (int c = 0; c < 64; c++) {
            float4 xv = *(float4*)&xs[c * 128 + nq * 4];
            float4 wv = *(float4*)&w1t[c * 32 + mseg * 4];
            o[0][0] = fmaf(wv.x, xv.x, o[0][0]); o[0][1] = fmaf(wv.x, xv.y, o[0][1]);
            o[0][2] = fmaf(wv.x, xv.z, o[0][2]); o[0][3] = fmaf(wv.x, xv.w, o[0][3]);
            o[1][0] = fmaf(wv.y, xv.x, o[1][0]); o[1][1] = fmaf(wv.y, xv.y, o[1][1]);
            o[1][2] = fmaf(wv.y, xv.z, o[1][2]); o[1][3] = fmaf(wv.y, xv.w, o[1][3]);
            o[2][0] = fmaf(wv.z, xv.x, o[2][0]); o[2][1] = fmaf(wv.z, xv.y, o[2][1]);
            o[2][2] = fmaf(wv.z, xv.z, o[2][2]); o[2][3] = fmaf(wv.z, xv.w, o[2][3]);
            o[3][0] = fmaf(wv.w, xv.x, o[3][0]); o[3][1] = fmaf(wv.w, xv.y, o[3][1]);
            o[3][2] = fmaf(wv.w, xv.z, o[3][2]); o[3][3] = fmaf(wv.w, xv.w, o[3][3]);
        }

        float s1 = 0.f, s2 = 0.f;
        #pragma unroll
        for (int mi = 0; mi < 4; mi++) {
            int m = m0 + mseg * 4 + mi;
            float bv = b1[m];
            float4 r;
            r.x = o[mi][0] + bv; r.y = o[mi][1] + bv;
            r.z = o[mi][2] + bv; r.w = o[mi][3] + bv;
            __half2 hA = __float22half2_rn(make_float2(r.x, r.y));
            __half2 hB = __float22half2_rn(make_float2(r.z, r.w));
            uint2 st8;
            st8.x = *(unsigned*)&hA; st8.y = *(unsigned*)&hB;
            *(uint2*)((char*)hH + (((size_t)(b * MM + m)) * NN + n0 + nq * 4) * 2) = st8;
            s1 += r.x + r.y + r.z + r.w;
            s2 = fmaf(r.x, r.x, s2); s2 = fmaf(r.y, r.y, s2);
            s2 = fmaf(r.z, r.z, s2); s2 = fmaf(r.w, r.w, s2);
        }
        for (int off = 32; off; off >>= 1) {
            s1 += __shfl_down(s1, off, 64);
            s2 += __shfl_down(s2, off, 64);
        }
        __syncthreads();                   // all waves past w1t reads -> alias r1/r2 on it
        float* r1 = w1t;
        float* r2 = w1t + 4;
        int w = t >> 6, l = t & 63;
        if (l == 0) { r1[w] = s1; r2[w] = s2; }
        __syncthreads();
        if (t == 0) {
            Mp[bx] = make_float2(r1[0] + r1[1] + r1[2] + r1[3],
                                 r2[0] + r2[1] + r2[2] + r2[3]);
        }
    } else {
        // ---- ballq body + cnt histogram (bx = blockIdx.x - 512) ----
        // fma-contraction safety: do NOT rewrite the distance expression tree.
        int bx = blockIdx.x - 512;
        int wid  = bx * 4 + (threadIdx.x >> 6);
        int lane = threadIdx.x & 63;
        int b = wid >> 12;
        int n = wid & 4095;
        const float* px = pos + b * 3 * NN;
        const float* py = px + NN;
        const float* pz = py + NN;
        float qx = px[n], qy = py[n], qz = pz[n];
        float qsq = qx*qx + qy*qy + qz*qz;
        int* row = idxb + (b * NN + n) * KK;
        int* cb = cnt + b * NN;

        int found = 0;
        int first = -1;
        const float R2 = 0.04f;
        for (int m0 = 0; m0 < NN && found < KK; m0 += 64) {
            int m = m0 + lane;
            float ax = px[m], ay = py[m], az = pz[m];
            float msq = ax*ax + ay*ay + az*az;
            float dot = qx*ax + qy*ay + qz*az;
            float d = qsq + msq - 2.0f * dot;
            bool hit = !(d > R2);
            unsigned long long mask = __ballot(hit);
            if (first < 0 && mask) first = m0 + (__ffsll((long long)mask) - 1);
            unsigned long long lt = (lane == 0) ? 0ULL : (mask & ((1ULL << lane) - 1ULL));
            int posh = __popcll(lt);
            if (hit && (found + posh) < KK) {
                row[found + posh] = m;
                atomicAdd(&cb[m], 1);      // accepted occurrence
            }
            found += __popcll(mask);
            if (found > KK) found = KK;
        }
        if (lane < KK && lane >= found) row[lane] = first;
        if (lane == 0 && found < KK) atomicAdd(&cb[first], KK - found);  // duplicated fills
    }
}

// ---------------- kernel B: gn1t + GN2-stat accumulation via cnt ----------------
// grid 512, block 256. Identical gn1t arithmetic; instead of writing R[j] partials
// for a separate gstats kernel, each block weights its 64 columns' group-sums by
// cnt[j] and atomically accumulates into GpS[b*8 + {g, 4+g}]. R and k_gstats die.
__global__ void k_gn1t(const __half* __restrict__ hH, const float* __restrict__ g1,
                       const float* __restrict__ be1, const float* __restrict__ wd,
                       const float2* __restrict__ Mp, __half* __restrict__ pH,
                       const int* __restrict__ cnt, float* __restrict__ GpS) {
    __shared__ float tile[64 * 65];
    __shared__ float mv[2];
    __shared__ float sAcc1, sAcc2;
    int t = threadIdx.x;

    int id = blockIdx.x;
    int n0 = (id & 63) * 64;
    int g  = (id >> 6) & 3;
    int b  = id >> 8;
    int m0 = g * 64;

    if (t == 0) { sAcc1 = 0.f; sAcc2 = 0.f; }
    if (t < 64) {
        float2 p2 = Mp[b * 256 + g * 64 + t];
        float s1 = p2.x, s2 = p2.y;
        for (int off = 32; off; off >>= 1) {
            s1 += __shfl_down(s1, off, 64);
            s2 += __shfl_down(s2, off, 64);
        }
        if (t == 0) {
            const double cntd = 64.0 * 4096.0;
            double md = (double)s1 / cntd;
            double vd = (double)s2 / cntd - md * md;
            mv[0] = (float)md;
            mv[1] = rsqrtf((float)vd + EPSF);
        }
    }
    __syncthreads();
    float mean = mv[0], rstd = mv[1];

    int nq = t & 15, mr = t >> 4;
    #pragma unroll
    for (int pp = 0; pp < 4; pp++) {
        int row = pp * 16 + mr;
        int m = m0 + row;
        float a = rstd * g1[m];
        float cc2 = be1[m] - mean * a;
        float wdm = wd[m];
        uint2 raw = *(const uint2*)((const char*)hH +
                     (((size_t)(b * MM + m)) * NN + n0 + nq * 4) * 2);
        float2 fa = __half22float2(*(__half2*)&raw.x);
        float2 fb = __half22float2(*(__half2*)&raw.y);
        tile[row * 65 + nq * 4 + 0] = gelu_exact(fmaf(fa.x, a, cc2)) * wdm;
        tile[row * 65 + nq * 4 + 1] = gelu_exact(fmaf(fa.y, a, cc2)) * wdm;
        tile[row * 65 + nq * 4 + 2] = gelu_exact(fmaf(fb.x, a, cc2)) * wdm;
        tile[row * 65 + nq * 4 + 3] = gelu_exact(fmaf(fb.y, a, cc2)) * wdm;
    }
    __syncthreads();
    #pragma unroll
    for (int pp = 0; pp < 4; pp++) {
        int id2 = pp * 256 + t;
        int nl = id2 >> 4, mq = id2 & 15;
        float a0 = tile[(mq * 4 + 0) * 65 + nl];
        float a1 = tile[(mq * 4 + 1) * 65 + nl];
        float a2 = tile[(mq * 4 + 2) * 65 + nl];
        float a3 = tile[(mq * 4 + 3) * 65 + nl];
        __half2 hA = __float22half2_rn(make_float2(a0, a1));
        __half2 hB = __float22half2_rn(make_float2(a2, a3));
        uint2 st8;
        st8.x = *(unsigned*)&hA; st8.y = *(unsigned*)&hB;
        *(uint2*)((char*)pH + ((((size_t)(b * NN) + n0 + nl)) << 9) + (m0 + mq * 4) * 2) = st8;
        float2 fa = __half22float2(hA);
        float2 fb = __half22float2(hB);
        float t1 = fa.x + fa.y + fb.x + fb.y;
        float t2 = fa.x * fa.x + fa.y * fa.y + fb.x * fb.x + fb.y * fb.y;
        #pragma unroll
        for (int off = 8; off; off >>= 1) {
            t1 += __shfl_down(t1, off, 16);
            t2 += __shfl_down(t2, off, 16);
        }
        if ((t & 15) == 0) {
            float cw = (float)cnt[b * NN + n0 + nl];
            atomicAdd(&sAcc1, cw * t1);
            atomicAdd(&sAcc2, cw * t2);
        }
    }
    __syncthreads();
    if (t == 0) {
        atomicAdd(&GpS[b * 8 + g],     sAcc1);
        atomicAdd(&GpS[b * 8 + 4 + g], sAcc2);
    }
}

// ---------------- kernel C: mlp2g (fused gather + GN2 + gelu + w2 matmul) ----------
// grid 512 (2 blocks/CU, LDS ~74KB), 4 cols/wave; XCD batch split. GN2 stats now
// come directly from GpS (8 floats/batch) -- the old 128-row Gp reduction is gone.
// GN3 partials go to OpS via 8 atomicAdds/block -- k_final's 256-row reduce is gone.
__global__ __launch_bounds__(256, 2)
void k_mlp2g(const __half* __restrict__ pH, const int* __restrict__ idxb,
             const float* __restrict__ GpS, const float* __restrict__ w2,
             const float* __restrict__ b2, const float* __restrict__ gd,
             const float* __restrict__ bed, float* __restrict__ oraw,
             float* __restrict__ OpS) {
    __shared__ float w2s[64 * 257];
    __shared__ uint4 phs4[4][4][32];   // [wave][col][32*uint4 = 256 half] per-wave scratch
    __shared__ float sA[4][4], sB[4][4];

    int t = threadIdx.x;
    int w = t >> 6, l = t & 63;
    int q = blockIdx.x;
    int b = ((q & 7) < 4) ? 0 : 1;
    int local = (q >> 3) * 4 + (q & 3);        // [0, 256), unique per batch
    int n0 = local * 16 + w * 4;

    #pragma unroll
    for (int p = 0; p < 16; p++) {
        int i = p * 256 + t;
        int c = i >> 6, mq = i & 63;
        float4 v = ((const float4*)w2)[i];
        float* dst = &w2s[c * 257 + mq * 4];
        dst[0] = v.x; dst[1] = v.y; dst[2] = v.z; dst[3] = v.w;
    }
    __syncthreads();

    int g = l >> 4;
    double s1 = (double)GpS[b * 8 + g];
    double s2 = (double)GpS[b * 8 + 4 + g];
    const double cnt2 = 64.0 * 4096.0 * 32.0;
    double m_ = s1 / cnt2;
    double v_ = s2 / cnt2 - m_ * m_;
    float mean = (float)m_;
    float rstd = rsqrtf((float)v_ + EPSF);
    float4 gd4  = ((const float4*)gd)[l];
    float4 bed4 = ((const float4*)bed)[l];
    float ax = rstd * gd4.x, ay = rstd * gd4.y, az = rstd * gd4.z, aw = rstd * gd4.w;
    float cx = bed4.x - mean * ax, cy = bed4.y - mean * ay;
    float cz = bed4.z - mean * az, cw = bed4.w - mean * aw;

    // ---- fused gather for this wave's 4 columns (bit-identical reduction) ----
    {
        int hh = l >> 5, cl = l & 31;
        const char* pb = (const char*)(pH + (size_t)b * NN * 256);
        int laneoff = cl * 16;
        const float4* g4 = (const float4*)gd;
        float4 gA = g4[cl * 2], gB = g4[cl * 2 + 1];
        #pragma unroll
        for (int p = 0; p < 4; p++) {
            int myidx = idxb[((size_t)(b * NN) + n0 + p) * KK + cl];
            unsigned vmax0 = 0xFC00FC00u, vmax1 = 0xFC00FC00u, vmax2 = 0xFC00FC00u, vmax3 = 0xFC00FC00u;
            unsigned vmin0 = 0x7C007C00u, vmin1 = 0x7C007C00u, vmin2 = 0x7C007C00u, vmin3 = 0x7C007C00u;
            #pragma unroll
            for (int kb = 0; kb < 4; kb++) {
                int jj[4];
                #pragma unroll
                for (int u = 0; u < 4; u++) {
                    int k = kb * 4 + u;
                    int ja = __shfl(myidx, 2 * k, 64);
                    int jb = __shfl(myidx, 2 * k + 1, 64);
                    jj[u] = hh ? jb : ja;
                }
                uint4 r[4];
                #pragma unroll
                for (int u = 0; u < 4; u++)
                    r[u] = *(const uint4*)(pb + (((size_t)jj[u]) << 9) + laneoff);
                #pragma unroll
                for (int u = 0; u < 4; u++) {
                    vmax0 = pkmax(vmax0, r[u].x); vmin0 = pkmin(vmin0, r[u].x);
                    vmax1 = pkmax(vmax1, r[u].y); vmin1 = pkmin(vmin1, r[u].y);
                    vmax2 = pkmax(vmax2, r[u].z); vmin2 = pkmin(vmin2, r[u].z);
                    vmax3 = pkmax(vmax3, r[u].w); vmin3 = pkmin(vmin3, r[u].w);
                }
            }
            vmax0 = pkmax(vmax0, (unsigned)__shfl_xor((int)vmax0, 32, 64));
            vmax1 = pkmax(vmax1, (unsigned)__shfl_xor((int)vmax1, 32, 64));
            vmax2 = pkmax(vmax2, (unsigned)__shfl_xor((int)vmax2, 32, 64));
            vmax3 = pkmax(vmax3, (unsigned)__shfl_xor((int)vmax3, 32, 64));
            vmin0 = pkmin(vmin0, (unsigned)__shfl_xor((int)vmin0, 32, 64));
            vmin1 = pkmin(vmin1, (unsigned)__shfl_xor((int)vmin1, 32, 64));
            vmin2 = pkmin(vmin2, (unsigned)__shfl_xor((int)vmin2, 32, 64));
            vmin3 = pkmin(vmin3, (unsigned)__shfl_xor((int)vmin3, 32, 64));

            if (hh == 0) {
                uint4 o4;
                o4.x = selpair(vmax0, vmin0, gA.x, gA.y);
                o4.y = selpair(vmax1, vmin1, gA.z, gA.w);
                o4.z = selpair(vmax2, vmin2, gB.x, gB.y);
                o4.w = selpair(vmax3, vmin3, gB.z, gB.w);
                phs4[w][p][cl] = o4;   // per-wave slot: same-wave RAW, no barrier
            }
        }
    }

    // ---- GN + gelu on the gathered columns ----
    float4 h2r[4];
    #pragma unroll
    for (int j = 0; j < 4; j++) {
        const uint2* pr = (const uint2*)&phs4[w][j][0];
        uint2 raw = pr[l];
        float2 fa = __half22float2(*(__half2*)&raw.x);
        float2 fb = __half22float2(*(__half2*)&raw.y);
        h2r[j].x = gelu_exact(fmaf(fa.x, ax, cx));
        h2r[j].y = gelu_exact(fmaf(fa.y, ay, cy));
        h2r[j].z = gelu_exact(fmaf(fb.x, az, cz));
        h2r[j].w = gelu_exact(fmaf(fb.y, aw, cw));
    }

    const float* w2l = &w2s[l * 257];
    float acc[4] = {0.f, 0.f, 0.f, 0.f};
    #pragma unroll 8
    for (int mq = 0; mq < 64; mq++) {
        float w0  = w2l[4 * mq + 0];
        float w1_ = w2l[4 * mq + 1];
        float w2_ = w2l[4 * mq + 2];
        float w3_ = w2l[4 * mq + 3];
        #pragma unroll
        for (int j = 0; j < 4; j++) {
            acc[j] = fmaf(w0,  bcast_lane(h2r[j].x, mq), acc[j]);
            acc[j] = fmaf(w1_, bcast_lane(h2r[j].y, mq), acc[j]);
            acc[j] = fmaf(w2_, bcast_lane(h2r[j].z, mq), acc[j]);
            acc[j] = fmaf(w3_, bcast_lane(h2r[j].w, mq), acc[j]);
        }
    }

    float bias = b2[l];
    float so1 = 0.f, so2 = 0.f;
    #pragma unroll
    for (int j = 0; j < 4; j++) {
        acc[j] += bias;
        so1 += acc[j];
        so2 = fmaf(acc[j], acc[j], so2);
    }
    *(float4*)&oraw[((size_t)(b * CC) + l) * NN + n0] =
        make_float4(acc[0], acc[1], acc[2], acc[3]);

    so1 += __shfl_down(so1, 8, 16); so2 += __shfl_down(so2, 8, 16);
    so1 += __shfl_down(so1, 4, 16); so2 += __shfl_down(so2, 4, 16);
    so1 += __shfl_down(so1, 2, 16); so2 += __shfl_down(so2, 2, 16);
    so1 += __shfl_down(so1, 1, 16); so2 += __shfl_down(so2, 1, 16);
    if ((l & 15) == 0) { sA[w][l >> 4] = so1; sB[w][l >> 4] = so2; }
    __syncthreads();
    if (t < 8) {
        int is2 = t >> 2, gg = t & 3;
        float v = is2 ? (sB[0][gg] + sB[1][gg] + sB[2][gg] + sB[3][gg])
                      : (sA[0][gg] + sA[1][gg] + sA[2][gg] + sA[3][gg]);
        atomicAdd(&OpS[b * 8 + t], v);
    }
}

// ---------------- kernel D: final (gn3 + residual), grid 512 x 256 ----------------
// GN3 stats read directly from OpS (8 floats/batch) -- no prologue reduction.
__global__ void k_final(const float* __restrict__ oraw, const float* __restrict__ x,
                        const float* __restrict__ g2, const float* __restrict__ be2,
                        const float* __restrict__ OpS, float* __restrict__ out) {
    int t = threadIdx.x;
    int i4 = blockIdx.x * 256 + t;
    int base = i4 * 4;
    int b = base >> 18;
    int c = (base >> 12) & 63;
    int g = c >> 4;

    double s1 = (double)OpS[b * 8 + g];
    double s2 = (double)OpS[b * 8 + 4 + g];
    const double cntd = 16.0 * 4096.0;
    double mean_d = s1 / cntd;
    double var_d  = s2 / cntd - mean_d * mean_d;
    float mean = (float)mean_d;
    float rstd = rsqrtf((float)var_d + EPSF);
    float sc = rstd * g2[c];
    float ad = be2[c] - mean * sc;
    float4 o = ((const float4*)oraw)[i4];
    float4 xv = ((const float4*)x)[i4];
    float4 r;
    r.x = fmaf(o.x, sc, ad) + xv.x;
    r.y = fmaf(o.y, sc, ad) + xv.y;
    r.z = fmaf(o.z, sc, ad) + xv.z;
    r.w = fmaf(o.w, sc, ad) + xv.w;
    ((float4*)out)[i4] = r;
}

// ---------------- launch ----------------
extern "C" void kernel_launch(void* const* d_in, const int* in_sizes, int n_in,
                              void* d_out, int out_size, void* d_ws, size_t ws_size,
                              hipStream_t stream) {
    const float* x   = (const float*)d_in[0];
    const float* pos = (const float*)d_in[1];
    const float* w1  = (const float*)d_in[2];
    const float* b1  = (const float*)d_in[3];
    const float* g1  = (const float*)d_in[4];
    const float* be1 = (const float*)d_in[5];
    const float* wd  = (const float*)d_in[6];
    const float* gd  = (const float*)d_in[7];
    const float* bed = (const float*)d_in[8];
    const float* w2  = (const float*)d_in[9];
    const float* b2  = (const float*)d_in[10];
    const float* g2  = (const float*)d_in[11];
    const float* be2 = (const float*)d_in[12];
    float* out = (float*)d_out;

    char* wsb = (char*)d_ws;
    __half* hH    = (__half*)wsb;                    // 4 MB (fp16 h)
    __half* pH    = (__half*)(wsb + 8388608);        // 4 MB
    float*  oraw  = (float*)(wsb + 16777216);        // 2 MB
    int*    idxb  = (int*)(wsb + 18874368);          // 1 MB
    float2* Mp    = (float2*)(wsb + 20185088);       // 4 KB
    int*    cnt   = (int*)(wsb + 20189184);          // 32 KB (2 x 4096 ints)
    float*  GpS   = (float*)(wsb + 20221952);        // 64 B  (2 x 8 floats)
    float*  OpS   = (float*)(wsb + 20222016);        // 64 B  (2 x 8 floats)

    // zero the atomic accumulators (cnt + GpS + OpS are contiguous: 32768+64+64)
    hipMemsetAsync((void*)cnt, 0, 32896, stream);

    k_mlp1_ballq<<<2560, 256, 0, stream>>>(x, w1, b1, hH, Mp, pos, idxb, cnt);
    k_gn1t<<<512, 256, 0, stream>>>(hH, g1, be1, wd, Mp, pH, cnt, GpS);
    k_mlp2g<<<512, 256, 0, stream>>>(pH, idxb, GpS, w2, b2, gd, bed, oraw, OpS);
    k_final<<<512, 256, 0, stream>>>(oraw, x, g2, be2, OpS, out);
}

// Round 5
// 202.084 us; speedup vs baseline: 3.6444x; 1.0613x over previous
//
#include <hip/hip_runtime.h>
#include <hip/hip_fp16.h>
#include <math.h>

#define BB 2
#define CC 64
#define NN 4096
#define MM 256
#define KK 32
#define GG 4
#define EPSF 1e-5f

__device__ __forceinline__ float gelu_exact(float x) {
    return 0.5f * x * (1.0f + erff(x * 0.70710678118654752f));
}

__device__ __forceinline__ unsigned pkmax(unsigned a, unsigned b) {
    unsigned d;
    asm("v_pk_max_f16 %0, %1, %2" : "=v"(d) : "v"(a), "v"(b));
    return d;
}
__device__ __forceinline__ unsigned pkmin(unsigned a, unsigned b) {
    unsigned d;
    asm("v_pk_min_f16 %0, %1, %2" : "=v"(d) : "v"(a), "v"(b));
    return d;
}
__device__ __forceinline__ unsigned selpair(unsigned mx, unsigned mn, float g0, float g1) {
    unsigned lo = (g0 >= 0.f) ? (mx & 0x0000FFFFu) : (mn & 0x0000FFFFu);
    unsigned hi = (g1 >= 0.f) ? (mx & 0xFFFF0000u) : (mn & 0xFFFF0000u);
    return lo | hi;
}
__device__ __forceinline__ float bcast_lane(float v, int lane) {
    return __int_as_float(__builtin_amdgcn_readlane(__float_as_int(v), lane));
}

// ---------------- kernel A: mlp1 (blocks 0..511) UNION ballq+cnt (512..2559) ----------
// R4 post-mortem: ballq's serial chain (load->ballot->found) at 16 waves/CU was 85us.
// Fix: two-phase bitmask ballq. Phase 1: 64 INDEPENDENT iterations compute per-lane
// hit bits (bit j = hit(point j*64+lane)) -- no ballot, no loop-carried state, loads
// pipeline 8-deep (ILP replaces the missing TLP). Phase 2: the ORIGINAL selection
// loop bit-for-bit (same ordering, same row/cnt writes, same early exit) but over
// register bits: ~30cy/iter instead of ~400cy.
// Distance expression tree byte-identical (fma-contraction safety).
__global__ void k_mlp1_ballq(const float* __restrict__ x, const float* __restrict__ w1,
                             const float* __restrict__ b1, __half* __restrict__ hH,
                             float2* __restrict__ Mp,
                             const float* __restrict__ pos, int* __restrict__ idxb,
                             int* __restrict__ cnt) {
    __shared__ __align__(16) float xs[64 * 128];
    __shared__ __align__(16) float w1t[64 * 32];
    int t = threadIdx.x;

    if (blockIdx.x < 512) {
        // ---- mlp1 body (identical arithmetic to the 145us version) ----
        int bx = blockIdx.x;
        int nt = bx & 31, mt = (bx >> 5) & 7, b = bx >> 8;
        int n0 = nt * 128, m0 = mt * 32;

        {
            int nq = t & 31, ch = t >> 5;
            #pragma unroll
            for (int p = 0; p < 8; p++) {
                int c = p * 8 + ch;
                float4 v = *(const float4*)&x[((size_t)(b * CC + c)) * NN + n0 + nq * 4];
                *(float4*)&xs[c * 128 + nq * 4] = v;
            }
        }
        {
            #pragma unroll
            for (int p = 0; p < 2; p++) {
                int idx = p * 256 + t;
                int m = idx >> 4, cq = idx & 15;
                float4 v = *(const float4*)&w1[(m0 + m) * CC + cq * 4];
                w1t[(cq * 4 + 0) * 32 + m] = v.x;
                w1t[(cq * 4 + 1) * 32 + m] = v.y;
                w1t[(cq * 4 + 2) * 32 + m] = v.z;
                w1t[(cq * 4 + 3) * 32 + m] = v.w;
            }
        }
        __syncthreads();

        int nq = t & 31;
        int mseg = t >> 5;
        float o[4][4];
        #pragma unroll
        for (int i = 0; i < 4; i++)
            #pragma unroll
            for (int j = 0; j < 4; j++) o[i][j] = 0.f;

        for (int c = 0; c < 64; c++) {
            float4 xv = *(float4*)&xs[c * 128 + nq * 4];
            float4 wv = *(float4*)&w1t[c * 32 + mseg * 4];
            o[0][0] = fmaf(wv.x, xv.x, o[0][0]); o[0][1] = fmaf(wv.x, xv.y, o[0][1]);
            o[0][2] = fmaf(wv.x, xv.z, o[0][2]); o[0][3] = fmaf(wv.x, xv.w, o[0][3]);
            o[1][0] = fmaf(wv.y, xv.x, o[1][0]); o[1][1] = fmaf(wv.y, xv.y, o[1][1]);
            o[1][2] = fmaf(wv.y, xv.z, o[1][2]); o[1][3] = fmaf(wv.y, xv.w, o[1][3]);
            o[2][0] = fmaf(wv.z, xv.x, o[2][0]); o[2][1] = fmaf(wv.z, xv.y, o[2][1]);
            o[2][2] = fmaf(wv.z, xv.z, o[2][2]); o[2][3] = fmaf(wv.z, xv.w, o[2][3]);
            o[3][0] = fmaf(wv.w, xv.x, o[3][0]); o[3][1] = fmaf(wv.w, xv.y, o[3][1]);
            o[3][2] = fmaf(wv.w, xv.z, o[3][2]); o[3][3] = fmaf(wv.w, xv.w, o[3][3]);
        }

        float s1 = 0.f, s2 = 0.f;
        #pragma unroll
        for (int mi = 0; mi < 4; mi++) {
            int m = m0 + mseg * 4 + mi;
            float bv = b1[m];
            float4 r;
            r.x = o[mi][0] + bv; r.y = o[mi][1] + bv;
            r.z = o[mi][2] + bv; r.w = o[mi][3] + bv;
            __half2 hA = __float22half2_rn(make_float2(r.x, r.y));
            __half2 hB = __float22half2_rn(make_float2(r.z, r.w));
            uint2 st8;
            st8.x = *(unsigned*)&hA; st8.y = *(unsigned*)&hB;
            *(uint2*)((char*)hH + (((size_t)(b * MM + m)) * NN + n0 + nq * 4) * 2) = st8;
            s1 += r.x + r.y + r.z + r.w;
            s2 = fmaf(r.x, r.x, s2); s2 = fmaf(r.y, r.y, s2);
            s2 = fmaf(r.z, r.z, s2); s2 = fmaf(r.w, r.w, s2);
        }
        for (int off = 32; off; off >>= 1) {
            s1 += __shfl_down(s1, off, 64);
            s2 += __shfl_down(s2, off, 64);
        }
        __syncthreads();                   // all waves past w1t reads -> alias r1/r2 on it
        float* r1 = w1t;
        float* r2 = w1t + 4;
        int w = t >> 6, l = t & 63;
        if (l == 0) { r1[w] = s1; r2[w] = s2; }
        __syncthreads();
        if (t == 0) {
            Mp[bx] = make_float2(r1[0] + r1[1] + r1[2] + r1[3],
                                 r2[0] + r2[1] + r2[2] + r2[3]);
        }
    } else {
        // ---- ballq body + cnt histogram, two-phase bitmask form ----
        int bx = blockIdx.x - 512;
        int wid  = bx * 4 + (threadIdx.x >> 6);
        int lane = threadIdx.x & 63;
        int b = wid >> 12;
        int n = wid & 4095;
        const float* px = pos + b * 3 * NN;
        const float* py = px + NN;
        const float* pz = py + NN;
        float qx = px[n], qy = py[n], qz = pz[n];
        float qsq = qx*qx + qy*qy + qz*qz;
        int* row = idxb + (b * NN + n) * KK;
        int* cb = cnt + b * NN;
        const float R2 = 0.04f;

        // phase 1: independent hit evaluation, per-lane bit j = hit(point j*64+lane)
        unsigned long long mybits = 0ULL;
        #pragma unroll 16
        for (int j = 0; j < 64; j++) {
            int m = j * 64 + lane;
            float ax = px[m], ay = py[m], az = pz[m];
            float msq = ax*ax + ay*ay + az*az;
            float dot = qx*ax + qy*ay + qz*az;
            float d = qsq + msq - 2.0f * dot;
            bool hit = !(d > R2);
            if (hit) mybits |= (1ULL << j);
        }

        // phase 2: original selection loop over register bits (bit-identical order)
        int found = 0;
        int first = -1;
        for (int j = 0; j < 64 && found < KK; j++) {
            bool hit = (mybits >> j) & 1ULL;
            int m = j * 64 + lane;
            unsigned long long mask = __ballot(hit);
            if (first < 0 && mask) first = j * 64 + (__ffsll((long long)mask) - 1);
            unsigned long long lt = (lane == 0) ? 0ULL : (mask & ((1ULL << lane) - 1ULL));
            int posh = __popcll(lt);
            if (hit && (found + posh) < KK) {
                row[found + posh] = m;
                atomicAdd(&cb[m], 1);      // accepted occurrence
            }
            found += __popcll(mask);
            if (found > KK) found = KK;
        }
        if (lane < KK && lane >= found) row[lane] = first;
        if (lane == 0 && found < KK) atomicAdd(&cb[first], KK - found);  // duplicated fills
    }
}

// ---------------- kernel B: gn1t + GN2-stat accumulation via cnt ----------------
// grid 512, block 256. Identical gn1t arithmetic; each block weights its 64 columns'
// group-sums by cnt[j] and atomically accumulates into GpS[b*8 + {g, 4+g}].
__global__ void k_gn1t(const __half* __restrict__ hH, const float* __restrict__ g1,
                       const float* __restrict__ be1, const float* __restrict__ wd,
                       const float2* __restrict__ Mp, __half* __restrict__ pH,
                       const int* __restrict__ cnt, float* __restrict__ GpS) {
    __shared__ float tile[64 * 65];
    __shared__ float mv[2];
    __shared__ float sAcc1, sAcc2;
    int t = threadIdx.x;

    int id = blockIdx.x;
    int n0 = (id & 63) * 64;
    int g  = (id >> 6) & 3;
    int b  = id >> 8;
    int m0 = g * 64;

    if (t == 0) { sAcc1 = 0.f; sAcc2 = 0.f; }
    if (t < 64) {
        float2 p2 = Mp[b * 256 + g * 64 + t];
        float s1 = p2.x, s2 = p2.y;
        for (int off = 32; off; off >>= 1) {
            s1 += __shfl_down(s1, off, 64);
            s2 += __shfl_down(s2, off, 64);
        }
        if (t == 0) {
            const double cntd = 64.0 * 4096.0;
            double md = (double)s1 / cntd;
            double vd = (double)s2 / cntd - md * md;
            mv[0] = (float)md;
            mv[1] = rsqrtf((float)vd + EPSF);
        }
    }
    __syncthreads();
    float mean = mv[0], rstd = mv[1];

    int nq = t & 15, mr = t >> 4;
    #pragma unroll
    for (int pp = 0; pp < 4; pp++) {
        int row = pp * 16 + mr;
        int m = m0 + row;
        float a = rstd * g1[m];
        float cc2 = be1[m] - mean * a;
        float wdm = wd[m];
        uint2 raw = *(const uint2*)((const char*)hH +
                     (((size_t)(b * MM + m)) * NN + n0 + nq * 4) * 2);
        float2 fa = __half22float2(*(__half2*)&raw.x);
        float2 fb = __half22float2(*(__half2*)&raw.y);
        tile[row * 65 + nq * 4 + 0] = gelu_exact(fmaf(fa.x, a, cc2)) * wdm;
        tile[row * 65 + nq * 4 + 1] = gelu_exact(fmaf(fa.y, a, cc2)) * wdm;
        tile[row * 65 + nq * 4 + 2] = gelu_exact(fmaf(fb.x, a, cc2)) * wdm;
        tile[row * 65 + nq * 4 + 3] = gelu_exact(fmaf(fb.y, a, cc2)) * wdm;
    }
    __syncthreads();
    #pragma unroll
    for (int pp = 0; pp < 4; pp++) {
        int id2 = pp * 256 + t;
        int nl = id2 >> 4, mq = id2 & 15;
        float a0 = tile[(mq * 4 + 0) * 65 + nl];
        float a1 = tile[(mq * 4 + 1) * 65 + nl];
        float a2 = tile[(mq * 4 + 2) * 65 + nl];
        float a3 = tile[(mq * 4 + 3) * 65 + nl];
        __half2 hA = __float22half2_rn(make_float2(a0, a1));
        __half2 hB = __float22half2_rn(make_float2(a2, a3));
        uint2 st8;
        st8.x = *(unsigned*)&hA; st8.y = *(unsigned*)&hB;
        *(uint2*)((char*)pH + ((((size_t)(b * NN) + n0 + nl)) << 9) + (m0 + mq * 4) * 2) = st8;
        float2 fa = __half22float2(hA);
        float2 fb = __half22float2(hB);
        float t1 = fa.x + fa.y + fb.x + fb.y;
        float t2 = fa.x * fa.x + fa.y * fa.y + fb.x * fb.x + fb.y * fb.y;
        #pragma unroll
        for (int off = 8; off; off >>= 1) {
            t1 += __shfl_down(t1, off, 16);
            t2 += __shfl_down(t2, off, 16);
        }
        if ((t & 15) == 0) {
            float cw = (float)cnt[b * NN + n0 + nl];
            atomicAdd(&sAcc1, cw * t1);
            atomicAdd(&sAcc2, cw * t2);
        }
    }
    __syncthreads();
    if (t == 0) {
        atomicAdd(&GpS[b * 8 + g],     sAcc1);
        atomicAdd(&GpS[b * 8 + 4 + g], sAcc2);
    }
}

// ---------------- kernel C: mlp2g (fused gather + GN2 + gelu + w2 matmul) ----------
// grid 512 (2 blocks/CU, LDS ~74KB), 4 cols/wave; XCD batch split. GN2 stats from
// GpS (8 floats/batch); GN3 partials to OpS via 8 atomicAdds/block.
__global__ __launch_bounds__(256, 2)
void k_mlp2g(const __half* __restrict__ pH, const int* __restrict__ idxb,
             const float* __restrict__ GpS, const float* __restrict__ w2,
             const float* __restrict__ b2, const float* __restrict__ gd,
             const float* __restrict__ bed, float* __restrict__ oraw,
             float* __restrict__ OpS) {
    __shared__ float w2s[64 * 257];
    __shared__ uint4 phs4[4][4][32];   // [wave][col][32*uint4 = 256 half] per-wave scratch
    __shared__ float sA[4][4], sB[4][4];

    int t = threadIdx.x;
    int w = t >> 6, l = t & 63;
    int q = blockIdx.x;
    int b = ((q & 7) < 4) ? 0 : 1;
    int local = (q >> 3) * 4 + (q & 3);        // [0, 256), unique per batch
    int n0 = local * 16 + w * 4;

    #pragma unroll
    for (int p = 0; p < 16; p++) {
        int i = p * 256 + t;
        int c = i >> 6, mq = i & 63;
        float4 v = ((const float4*)w2)[i];
        float* dst = &w2s[c * 257 + mq * 4];
        dst[0] = v.x; dst[1] = v.y; dst[2] = v.z; dst[3] = v.w;
    }
    __syncthreads();

    int g = l >> 4;
    double s1 = (double)GpS[b * 8 + g];
    double s2 = (double)GpS[b * 8 + 4 + g];
    const double cnt2 = 64.0 * 4096.0 * 32.0;
    double m_ = s1 / cnt2;
    double v_ = s2 / cnt2 - m_ * m_;
    float mean = (float)m_;
    float rstd = rsqrtf((float)v_ + EPSF);
    float4 gd4  = ((const float4*)gd)[l];
    float4 bed4 = ((const float4*)bed)[l];
    float ax = rstd * gd4.x, ay = rstd * gd4.y, az = rstd * gd4.z, aw = rstd * gd4.w;
    float cx = bed4.x - mean * ax, cy = bed4.y - mean * ay;
    float cz = bed4.z - mean * az, cw = bed4.w - mean * aw;

    // ---- fused gather for this wave's 4 columns (bit-identical reduction) ----
    {
        int hh = l >> 5, cl = l & 31;
        const char* pb = (const char*)(pH + (size_t)b * NN * 256);
        int laneoff = cl * 16;
        const float4* g4 = (const float4*)gd;
        float4 gA = g4[cl * 2], gB = g4[cl * 2 + 1];
        #pragma unroll
        for (int p = 0; p < 4; p++) {
            int myidx = idxb[((size_t)(b * NN) + n0 + p) * KK + cl];
            unsigned vmax0 = 0xFC00FC00u, vmax1 = 0xFC00FC00u, vmax2 = 0xFC00FC00u, vmax3 = 0xFC00FC00u;
            unsigned vmin0 = 0x7C007C00u, vmin1 = 0x7C007C00u, vmin2 = 0x7C007C00u, vmin3 = 0x7C007C00u;
            #pragma unroll
            for (int kb = 0; kb < 4; kb++) {
                int jj[4];
                #pragma unroll
                for (int u = 0; u < 4; u++) {
                    int k = kb * 4 + u;
                    int ja = __shfl(myidx, 2 * k, 64);
                    int jb = __shfl(myidx, 2 * k + 1, 64);
                    jj[u] = hh ? jb : ja;
                }
                uint4 r[4];
                #pragma unroll
                for (int u = 0; u < 4; u++)
                    r[u] = *(const uint4*)(pb + (((size_t)jj[u]) << 9) + laneoff);
                #pragma unroll
                for (int u = 0; u < 4; u++) {
                    vmax0 = pkmax(vmax0, r[u].x); vmin0 = pkmin(vmin0, r[u].x);
                    vmax1 = pkmax(vmax1, r[u].y); vmin1 = pkmin(vmin1, r[u].y);
                    vmax2 = pkmax(vmax2, r[u].z); vmin2 = pkmin(vmin2, r[u].z);
                    vmax3 = pkmax(vmax3, r[u].w); vmin3 = pkmin(vmin3, r[u].w);
                }
            }
            vmax0 = pkmax(vmax0, (unsigned)__shfl_xor((int)vmax0, 32, 64));
            vmax1 = pkmax(vmax1, (unsigned)__shfl_xor((int)vmax1, 32, 64));
            vmax2 = pkmax(vmax2, (unsigned)__shfl_xor((int)vmax2, 32, 64));
            vmax3 = pkmax(vmax3, (unsigned)__shfl_xor((int)vmax3, 32, 64));
            vmin0 = pkmin(vmin0, (unsigned)__shfl_xor((int)vmin0, 32, 64));
            vmin1 = pkmin(vmin1, (unsigned)__shfl_xor((int)vmin1, 32, 64));
            vmin2 = pkmin(vmin2, (unsigned)__shfl_xor((int)vmin2, 32, 64));
            vmin3 = pkmin(vmin3, (unsigned)__shfl_xor((int)vmin3, 32, 64));

            if (hh == 0) {
                uint4 o4;
                o4.x = selpair(vmax0, vmin0, gA.x, gA.y);
                o4.y = selpair(vmax1, vmin1, gA.z, gA.w);
                o4.z = selpair(vmax2, vmin2, gB.x, gB.y);
                o4.w = selpair(vmax3, vmin3, gB.z, gB.w);
                phs4[w][p][cl] = o4;   // per-wave slot: same-wave RAW, no barrier
            }
        }
    }

    // ---- GN + gelu on the gathered columns ----
    float4 h2r[4];
    #pragma unroll
    for (int j = 0; j < 4; j++) {
        const uint2* pr = (const uint2*)&phs4[w][j][0];
        uint2 raw = pr[l];
        float2 fa = __half22float2(*(__half2*)&raw.x);
        float2 fb = __half22float2(*(__half2*)&raw.y);
        h2r[j].x = gelu_exact(fmaf(fa.x, ax, cx));
        h2r[j].y = gelu_exact(fmaf(fa.y, ay, cy));
        h2r[j].z = gelu_exact(fmaf(fb.x, az, cz));
        h2r[j].w = gelu_exact(fmaf(fb.y, aw, cw));
    }

    const float* w2l = &w2s[l * 257];
    float acc[4] = {0.f, 0.f, 0.f, 0.f};
    #pragma unroll 8
    for (int mq = 0; mq < 64; mq++) {
        float w0  = w2l[4 * mq + 0];
        float w1_ = w2l[4 * mq + 1];
        float w2_ = w2l[4 * mq + 2];
        float w3_ = w2l[4 * mq + 3];
        #pragma unroll
        for (int j = 0; j < 4; j++) {
            acc[j] = fmaf(w0,  bcast_lane(h2r[j].x, mq), acc[j]);
            acc[j] = fmaf(w1_, bcast_lane(h2r[j].y, mq), acc[j]);
            acc[j] = fmaf(w2_, bcast_lane(h2r[j].z, mq), acc[j]);
            acc[j] = fmaf(w3_, bcast_lane(h2r[j].w, mq), acc[j]);
        }
    }

    float bias = b2[l];
    float so1 = 0.f, so2 = 0.f;
    #pragma unroll
    for (int j = 0; j < 4; j++) {
        acc[j] += bias;
        so1 += acc[j];
        so2 = fmaf(acc[j], acc[j], so2);
    }
    *(float4*)&oraw[((size_t)(b * CC) + l) * NN + n0] =
        make_float4(acc[0], acc[1], acc[2], acc[3]);

    so1 += __shfl_down(so1, 8, 16); so2 += __shfl_down(so2, 8, 16);
    so1 += __shfl_down(so1, 4, 16); so2 += __shfl_down(so2, 4, 16);
    so1 += __shfl_down(so1, 2, 16); so2 += __shfl_down(so2, 2, 16);
    so1 += __shfl_down(so1, 1, 16); so2 += __shfl_down(so2, 1, 16);
    if ((l & 15) == 0) { sA[w][l >> 4] = so1; sB[w][l >> 4] = so2; }
    __syncthreads();
    if (t < 8) {
        int is2 = t >> 2, gg = t & 3;
        float v = is2 ? (sB[0][gg] + sB[1][gg] + sB[2][gg] + sB[3][gg])
                      : (sA[0][gg] + sA[1][gg] + sA[2][gg] + sA[3][gg]);
        atomicAdd(&OpS[b * 8 + t], v);
    }
}

// ---------------- kernel D: final (gn3 + residual), grid 512 x 256 ----------------
__global__ void k_final(const float* __restrict__ oraw, const float* __restrict__ x,
                        const float* __restrict__ g2, const float* __restrict__ be2,
                        const float* __restrict__ OpS, float* __restrict__ out) {
    int t = threadIdx.x;
    int i4 = blockIdx.x * 256 + t;
    int base = i4 * 4;
    int b = base >> 18;
    int c = (base >> 12) & 63;
    int g = c >> 4;

    double s1 = (double)OpS[b * 8 + g];
    double s2 = (double)OpS[b * 8 + 4 + g];
    const double cntd = 16.0 * 4096.0;
    double mean_d = s1 / cntd;
    double var_d  = s2 / cntd - mean_d * mean_d;
    float mean = (float)mean_d;
    float rstd = rsqrtf((float)var_d + EPSF);
    float sc = rstd * g2[c];
    float ad = be2[c] - mean * sc;
    float4 o = ((const float4*)oraw)[i4];
    float4 xv = ((const float4*)x)[i4];
    float4 r;
    r.x = fmaf(o.x, sc, ad) + xv.x;
    r.y = fmaf(o.y, sc, ad) + xv.y;
    r.z = fmaf(o.z, sc, ad) + xv.z;
    r.w = fmaf(o.w, sc, ad) + xv.w;
    ((float4*)out)[i4] = r;
}

// ---------------- launch ----------------
extern "C" void kernel_launch(void* const* d_in, const int* in_sizes, int n_in,
                              void* d_out, int out_size, void* d_ws, size_t ws_size,
                              hipStream_t stream) {
    const float* x   = (const float*)d_in[0];
    const float* pos = (const float*)d_in[1];
    const float* w1  = (const float*)d_in[2];
    const float* b1  = (const float*)d_in[3];
    const float* g1  = (const float*)d_in[4];
    const float* be1 = (const float*)d_in[5];
    const float* wd  = (const float*)d_in[6];
    const float* gd  = (const float*)d_in[7];
    const float* bed = (const float*)d_in[8];
    const float* w2  = (const float*)d_in[9];
    const float* b2  = (const float*)d_in[10];
    const float* g2  = (const float*)d_in[11];
    const float* be2 = (const float*)d_in[12];
    float* out = (float*)d_out;

    char* wsb = (char*)d_ws;
    __half* hH    = (__half*)wsb;                    // 4 MB (fp16 h)
    __half* pH    = (__half*)(wsb + 8388608);        // 4 MB
    float*  oraw  = (float*)(wsb + 16777216);        // 2 MB
    int*    idxb  = (int*)(wsb + 18874368);          // 1 MB
    float2* Mp    = (float2*)(wsb + 20185088);       // 4 KB
    int*    cnt   = (int*)(wsb + 20189184);          // 32 KB (2 x 4096 ints)
    float*  GpS   = (float*)(wsb + 20221952);        // 64 B  (2 x 8 floats)
    float*  OpS   = (float*)(wsb + 20222016);        // 64 B  (2 x 8 floats)

    // zero the atomic accumulators (cnt + GpS + OpS are contiguous: 32768+64+64)
    hipMemsetAsync((void*)cnt, 0, 32896, stream);

    k_mlp1_ballq<<<2560, 256, 0, stream>>>(x, w1, b1, hH, Mp, pos, idxb, cnt);
    k_gn1t<<<512, 256, 0, stream>>>(hH, g1, be1, wd, Mp, pH, cnt, GpS);
    k_mlp2g<<<512, 256, 0, stream>>>(pH, idxb, GpS, w2, b2, gd, bed, oraw, OpS);
    k_final<<<512, 256, 0, stream>>>(oraw, x, g2, be2, OpS, out);
}

// Round 6
// 198.331 us; speedup vs baseline: 3.7133x; 1.0189x over previous
//
#include <hip/hip_runtime.h>
#include <hip/hip_fp16.h>
#include <math.h>

#define BB 2
#define CC 64
#define NN 4096
#define MM 256
#define KK 32
#define GG 4
#define EPSF 1e-5f

__device__ __forceinline__ float gelu_exact(float x) {
    return 0.5f * x * (1.0f + erff(x * 0.70710678118654752f));
}

__device__ __forceinline__ unsigned pkmax(unsigned a, unsigned b) {
    unsigned d;
    asm("v_pk_max_f16 %0, %1, %2" : "=v"(d) : "v"(a), "v"(b));
    return d;
}
__device__ __forceinline__ unsigned pkmin(unsigned a, unsigned b) {
    unsigned d;
    asm("v_pk_min_f16 %0, %1, %2" : "=v"(d) : "v"(a), "v"(b));
    return d;
}
__device__ __forceinline__ unsigned selpair(unsigned mx, unsigned mn, float g0, float g1) {
    unsigned lo = (g0 >= 0.f) ? (mx & 0x0000FFFFu) : (mn & 0x0000FFFFu);
    unsigned hi = (g1 >= 0.f) ? (mx & 0xFFFF0000u) : (mn & 0xFFFF0000u);
    return lo | hi;
}
__device__ __forceinline__ float bcast_lane(float v, int lane) {
    return __int_as_float(__builtin_amdgcn_readlane(__float_as_int(v), lane));
}

// ---------------- kernel A: mlp1 (blocks 0..511) UNION ballq+cnt (512..2559) ----------
// R5 post-mortem: ballq blocks carried mlp1's 40KB LDS -> 16 waves/CU for a pure
// latency chain (Occupancy 29%, VALUBusy 25%). Fix: LDS cut to w1t only (8.25KB) by
// reading x DIRECT from global in the mlp1 FMA loop (512B-contiguous per wave at
// fixed c; 32KB/block working set -> L1/L2 hits). 8 blocks/CU = 32 waves/CU now.
// launch_bounds(256,8) pins VGPR<=64 so ballq phase-1 batches ~16 loads in flight.
// ballq body byte-identical to R5 (distance tree untouched -- fma-contraction safe).
__global__ __launch_bounds__(256, 8)
void k_mlp1_ballq(const float* __restrict__ x, const float* __restrict__ w1,
                  const float* __restrict__ b1, __half* __restrict__ hH,
                  float2* __restrict__ Mp,
                  const float* __restrict__ pos, int* __restrict__ idxb,
                  int* __restrict__ cnt) {
    __shared__ __align__(16) float w1t[64 * 32 + 8];
    int t = threadIdx.x;

    if (blockIdx.x < 512) {
        // ---- mlp1 body (identical arithmetic; xs staging removed) ----
        int bx = blockIdx.x;
        int nt = bx & 31, mt = (bx >> 5) & 7, b = bx >> 8;
        int n0 = nt * 128, m0 = mt * 32;

        {
            #pragma unroll
            for (int p = 0; p < 2; p++) {
                int idx = p * 256 + t;
                int m = idx >> 4, cq = idx & 15;
                float4 v = *(const float4*)&w1[(m0 + m) * CC + cq * 4];
                w1t[(cq * 4 + 0) * 32 + m] = v.x;
                w1t[(cq * 4 + 1) * 32 + m] = v.y;
                w1t[(cq * 4 + 2) * 32 + m] = v.z;
                w1t[(cq * 4 + 3) * 32 + m] = v.w;
            }
        }
        __syncthreads();

        int nq = t & 31;
        int mseg = t >> 5;
        const float* xb = &x[((size_t)(b * CC)) * NN + n0 + nq * 4];
        float o[4][4];
        #pragma unroll
        for (int i = 0; i < 4; i++)
            #pragma unroll
            for (int j = 0; j < 4; j++) o[i][j] = 0.f;

        #pragma unroll 4
        for (int c = 0; c < 64; c++) {
            float4 xv = *(const float4*)&xb[(size_t)c * NN];
            float4 wv = *(float4*)&w1t[c * 32 + mseg * 4];
            o[0][0] = fmaf(wv.x, xv.x, o[0][0]); o[0][1] = fmaf(wv.x, xv.y, o[0][1]);
            o[0][2] = fmaf(wv.x, xv.z, o[0][2]); o[0][3] = fmaf(wv.x, xv.w, o[0][3]);
            o[1][0] = fmaf(wv.y, xv.x, o[1][0]); o[1][1] = fmaf(wv.y, xv.y, o[1][1]);
            o[1][2] = fmaf(wv.y, xv.z, o[1][2]); o[1][3] = fmaf(wv.y, xv.w, o[1][3]);
            o[2][0] = fmaf(wv.z, xv.x, o[2][0]); o[2][1] = fmaf(wv.z, xv.y, o[2][1]);
            o[2][2] = fmaf(wv.z, xv.z, o[2][2]); o[2][3] = fmaf(wv.z, xv.w, o[2][3]);
            o[3][0] = fmaf(wv.w, xv.x, o[3][0]); o[3][1] = fmaf(wv.w, xv.y, o[3][1]);
            o[3][2] = fmaf(wv.w, xv.z, o[3][2]); o[3][3] = fmaf(wv.w, xv.w, o[3][3]);
        }

        float s1 = 0.f, s2 = 0.f;
        #pragma unroll
        for (int mi = 0; mi < 4; mi++) {
            int m = m0 + mseg * 4 + mi;
            float bv = b1[m];
            float4 r;
            r.x = o[mi][0] + bv; r.y = o[mi][1] + bv;
            r.z = o[mi][2] + bv; r.w = o[mi][3] + bv;
            __half2 hA = __float22half2_rn(make_float2(r.x, r.y));
            __half2 hB = __float22half2_rn(make_float2(r.z, r.w));
            uint2 st8;
            st8.x = *(unsigned*)&hA; st8.y = *(unsigned*)&hB;
            *(uint2*)((char*)hH + (((size_t)(b * MM + m)) * NN + n0 + nq * 4) * 2) = st8;
            s1 += r.x + r.y + r.z + r.w;
            s2 = fmaf(r.x, r.x, s2); s2 = fmaf(r.y, r.y, s2);
            s2 = fmaf(r.z, r.z, s2); s2 = fmaf(r.w, r.w, s2);
        }
        for (int off = 32; off; off >>= 1) {
            s1 += __shfl_down(s1, off, 64);
            s2 += __shfl_down(s2, off, 64);
        }
        __syncthreads();                   // all waves past w1t reads -> alias r1/r2 on it
        float* r1 = w1t + 64 * 32;
        float* r2 = r1 + 4;
        int w = t >> 6, l = t & 63;
        if (l == 0) { r1[w] = s1; r2[w] = s2; }
        __syncthreads();
        if (t == 0) {
            Mp[bx] = make_float2(r1[0] + r1[1] + r1[2] + r1[3],
                                 r2[0] + r2[1] + r2[2] + r2[3]);
        }
    } else {
        // ---- ballq body + cnt histogram, two-phase bitmask form (byte-identical R5) ----
        int bx = blockIdx.x - 512;
        int wid  = bx * 4 + (threadIdx.x >> 6);
        int lane = threadIdx.x & 63;
        int b = wid >> 12;
        int n = wid & 4095;
        const float* px = pos + b * 3 * NN;
        const float* py = px + NN;
        const float* pz = py + NN;
        float qx = px[n], qy = py[n], qz = pz[n];
        float qsq = qx*qx + qy*qy + qz*qz;
        int* row = idxb + (b * NN + n) * KK;
        int* cb = cnt + b * NN;
        const float R2 = 0.04f;

        // phase 1: independent hit evaluation, per-lane bit j = hit(point j*64+lane)
        unsigned long long mybits = 0ULL;
        #pragma unroll 16
        for (int j = 0; j < 64; j++) {
            int m = j * 64 + lane;
            float ax = px[m], ay = py[m], az = pz[m];
            float msq = ax*ax + ay*ay + az*az;
            float dot = qx*ax + qy*ay + qz*az;
            float d = qsq + msq - 2.0f * dot;
            bool hit = !(d > R2);
            if (hit) mybits |= (1ULL << j);
        }

        // phase 2: original selection loop over register bits (bit-identical order)
        int found = 0;
        int first = -1;
        for (int j = 0; j < 64 && found < KK; j++) {
            bool hit = (mybits >> j) & 1ULL;
            int m = j * 64 + lane;
            unsigned long long mask = __ballot(hit);
            if (first < 0 && mask) first = j * 64 + (__ffsll((long long)mask) - 1);
            unsigned long long lt = (lane == 0) ? 0ULL : (mask & ((1ULL << lane) - 1ULL));
            int posh = __popcll(lt);
            if (hit && (found + posh) < KK) {
                row[found + posh] = m;
                atomicAdd(&cb[m], 1);      // accepted occurrence
            }
            found += __popcll(mask);
            if (found > KK) found = KK;
        }
        if (lane < KK && lane >= found) row[lane] = first;
        if (lane == 0 && found < KK) atomicAdd(&cb[first], KK - found);  // duplicated fills
    }
}

// ---------------- kernel B: gn1t + GN2-stat accumulation via cnt ----------------
// grid 512, block 256. Identical gn1t arithmetic; each block weights its 64 columns'
// group-sums by cnt[j] and atomically accumulates into GpS[b*8 + {g, 4+g}].
__global__ void k_gn1t(const __half* __restrict__ hH, const float* __restrict__ g1,
                       const float* __restrict__ be1, const float* __restrict__ wd,
                       const float2* __restrict__ Mp, __half* __restrict__ pH,
                       const int* __restrict__ cnt, float* __restrict__ GpS) {
    __shared__ float tile[64 * 65];
    __shared__ float mv[2];
    __shared__ float sAcc1, sAcc2;
    int t = threadIdx.x;

    int id = blockIdx.x;
    int n0 = (id & 63) * 64;
    int g  = (id >> 6) & 3;
    int b  = id >> 8;
    int m0 = g * 64;

    if (t == 0) { sAcc1 = 0.f; sAcc2 = 0.f; }
    if (t < 64) {
        float2 p2 = Mp[b * 256 + g * 64 + t];
        float s1 = p2.x, s2 = p2.y;
        for (int off = 32; off; off >>= 1) {
            s1 += __shfl_down(s1, off, 64);
            s2 += __shfl_down(s2, off, 64);
        }
        if (t == 0) {
            const double cntd = 64.0 * 4096.0;
            double md = (double)s1 / cntd;
            double vd = (double)s2 / cntd - md * md;
            mv[0] = (float)md;
            mv[1] = rsqrtf((float)vd + EPSF);
        }
    }
    __syncthreads();
    float mean = mv[0], rstd = mv[1];

    int nq = t & 15, mr = t >> 4;
    #pragma unroll
    for (int pp = 0; pp < 4; pp++) {
        int row = pp * 16 + mr;
        int m = m0 + row;
        float a = rstd * g1[m];
        float cc2 = be1[m] - mean * a;
        float wdm = wd[m];
        uint2 raw = *(const uint2*)((const char*)hH +
                     (((size_t)(b * MM + m)) * NN + n0 + nq * 4) * 2);
        float2 fa = __half22float2(*(__half2*)&raw.x);
        float2 fb = __half22float2(*(__half2*)&raw.y);
        tile[row * 65 + nq * 4 + 0] = gelu_exact(fmaf(fa.x, a, cc2)) * wdm;
        tile[row * 65 + nq * 4 + 1] = gelu_exact(fmaf(fa.y, a, cc2)) * wdm;
        tile[row * 65 + nq * 4 + 2] = gelu_exact(fmaf(fb.x, a, cc2)) * wdm;
        tile[row * 65 + nq * 4 + 3] = gelu_exact(fmaf(fb.y, a, cc2)) * wdm;
    }
    __syncthreads();
    #pragma unroll
    for (int pp = 0; pp < 4; pp++) {
        int id2 = pp * 256 + t;
        int nl = id2 >> 4, mq = id2 & 15;
        float a0 = tile[(mq * 4 + 0) * 65 + nl];
        float a1 = tile[(mq * 4 + 1) * 65 + nl];
        float a2 = tile[(mq * 4 + 2) * 65 + nl];
        float a3 = tile[(mq * 4 + 3) * 65 + nl];
        __half2 hA = __float22half2_rn(make_float2(a0, a1));
        __half2 hB = __float22half2_rn(make_float2(a2, a3));
        uint2 st8;
        st8.x = *(unsigned*)&hA; st8.y = *(unsigned*)&hB;
        *(uint2*)((char*)pH + ((((size_t)(b * NN) + n0 + nl)) << 9) + (m0 + mq * 4) * 2) = st8;
        float2 fa = __half22float2(hA);
        float2 fb = __half22float2(hB);
        float t1 = fa.x + fa.y + fb.x + fb.y;
        float t2 = fa.x * fa.x + fa.y * fa.y + fb.x * fb.x + fb.y * fb.y;
        #pragma unroll
        for (int off = 8; off; off >>= 1) {
            t1 += __shfl_down(t1, off, 16);
            t2 += __shfl_down(t2, off, 16);
        }
        if ((t & 15) == 0) {
            float cw = (float)cnt[b * NN + n0 + nl];
            atomicAdd(&sAcc1, cw * t1);
            atomicAdd(&sAcc2, cw * t2);
        }
    }
    __syncthreads();
    if (t == 0) {
        atomicAdd(&GpS[b * 8 + g],     sAcc1);
        atomicAdd(&GpS[b * 8 + 4 + g], sAcc2);
    }
}

// ---------------- kernel C: mlp2g (fused gather + GN2 + gelu + w2 matmul) ----------
// grid 512 (2 blocks/CU, LDS ~74KB), 4 cols/wave; XCD batch split. GN2 stats from
// GpS (8 floats/batch); GN3 partials to OpS via 8 atomicAdds/block.
__global__ __launch_bounds__(256, 2)
void k_mlp2g(const __half* __restrict__ pH, const int* __restrict__ idxb,
             const float* __restrict__ GpS, const float* __restrict__ w2,
             const float* __restrict__ b2, const float* __restrict__ gd,
             const float* __restrict__ bed, float* __restrict__ oraw,
             float* __restrict__ OpS) {
    __shared__ float w2s[64 * 257];
    __shared__ uint4 phs4[4][4][32];   // [wave][col][32*uint4 = 256 half] per-wave scratch
    __shared__ float sA[4][4], sB[4][4];

    int t = threadIdx.x;
    int w = t >> 6, l = t & 63;
    int q = blockIdx.x;
    int b = ((q & 7) < 4) ? 0 : 1;
    int local = (q >> 3) * 4 + (q & 3);        // [0, 256), unique per batch
    int n0 = local * 16 + w * 4;

    #pragma unroll
    for (int p = 0; p < 16; p++) {
        int i = p * 256 + t;
        int c = i >> 6, mq = i & 63;
        float4 v = ((const float4*)w2)[i];
        float* dst = &w2s[c * 257 + mq * 4];
        dst[0] = v.x; dst[1] = v.y; dst[2] = v.z; dst[3] = v.w;
    }
    __syncthreads();

    int g = l >> 4;
    double s1 = (double)GpS[b * 8 + g];
    double s2 = (double)GpS[b * 8 + 4 + g];
    const double cnt2 = 64.0 * 4096.0 * 32.0;
    double m_ = s1 / cnt2;
    double v_ = s2 / cnt2 - m_ * m_;
    float mean = (float)m_;
    float rstd = rsqrtf((float)v_ + EPSF);
    float4 gd4  = ((const float4*)gd)[l];
    float4 bed4 = ((const float4*)bed)[l];
    float ax = rstd * gd4.x, ay = rstd * gd4.y, az = rstd * gd4.z, aw = rstd * gd4.w;
    float cx = bed4.x - mean * ax, cy = bed4.y - mean * ay;
    float cz = bed4.z - mean * az, cw = bed4.w - mean * aw;

    // ---- fused gather for this wave's 4 columns (bit-identical reduction) ----
    {
        int hh = l >> 5, cl = l & 31;
        const char* pb = (const char*)(pH + (size_t)b * NN * 256);
        int laneoff = cl * 16;
        const float4* g4 = (const float4*)gd;
        float4 gA = g4[cl * 2], gB = g4[cl * 2 + 1];
        #pragma unroll
        for (int p = 0; p < 4; p++) {
            int myidx = idxb[((size_t)(b * NN) + n0 + p) * KK + cl];
            unsigned vmax0 = 0xFC00FC00u, vmax1 = 0xFC00FC00u, vmax2 = 0xFC00FC00u, vmax3 = 0xFC00FC00u;
            unsigned vmin0 = 0x7C007C00u, vmin1 = 0x7C007C00u, vmin2 = 0x7C007C00u, vmin3 = 0x7C007C00u;
            #pragma unroll
            for (int kb = 0; kb < 4; kb++) {
                int jj[4];
                #pragma unroll
                for (int u = 0; u < 4; u++) {
                    int k = kb * 4 + u;
                    int ja = __shfl(myidx, 2 * k, 64);
                    int jb = __shfl(myidx, 2 * k + 1, 64);
                    jj[u] = hh ? jb : ja;
                }
                uint4 r[4];
                #pragma unroll
                for (int u = 0; u < 4; u++)
                    r[u] = *(const uint4*)(pb + (((size_t)jj[u]) << 9) + laneoff);
                #pragma unroll
                for (int u = 0; u < 4; u++) {
                    vmax0 = pkmax(vmax0, r[u].x); vmin0 = pkmin(vmin0, r[u].x);
                    vmax1 = pkmax(vmax1, r[u].y); vmin1 = pkmin(vmin1, r[u].y);
                    vmax2 = pkmax(vmax2, r[u].z); vmin2 = pkmin(vmin2, r[u].z);
                    vmax3 = pkmax(vmax3, r[u].w); vmin3 = pkmin(vmin3, r[u].w);
                }
            }
            vmax0 = pkmax(vmax0, (unsigned)__shfl_xor((int)vmax0, 32, 64));
            vmax1 = pkmax(vmax1, (unsigned)__shfl_xor((int)vmax1, 32, 64));
            vmax2 = pkmax(vmax2, (unsigned)__shfl_xor((int)vmax2, 32, 64));
            vmax3 = pkmax(vmax3, (unsigned)__shfl_xor((int)vmax3, 32, 64));
            vmin0 = pkmin(vmin0, (unsigned)__shfl_xor((int)vmin0, 32, 64));
            vmin1 = pkmin(vmin1, (unsigned)__shfl_xor((int)vmin1, 32, 64));
            vmin2 = pkmin(vmin2, (unsigned)__shfl_xor((int)vmin2, 32, 64));
            vmin3 = pkmin(vmin3, (unsigned)__shfl_xor((int)vmin3, 32, 64));

            if (hh == 0) {
                uint4 o4;
                o4.x = selpair(vmax0, vmin0, gA.x, gA.y);
                o4.y = selpair(vmax1, vmin1, gA.z, gA.w);
                o4.z = selpair(vmax2, vmin2, gB.x, gB.y);
                o4.w = selpair(vmax3, vmin3, gB.z, gB.w);
                phs4[w][p][cl] = o4;   // per-wave slot: same-wave RAW, no barrier
            }
        }
    }

    // ---- GN + gelu on the gathered columns ----
    float4 h2r[4];
    #pragma unroll
    for (int j = 0; j < 4; j++) {
        const uint2* pr = (const uint2*)&phs4[w][j][0];
        uint2 raw = pr[l];
        float2 fa = __half22float2(*(__half2*)&raw.x);
        float2 fb = __half22float2(*(__half2*)&raw.y);
        h2r[j].x = gelu_exact(fmaf(fa.x, ax, cx));
        h2r[j].y = gelu_exact(fmaf(fa.y, ay, cy));
        h2r[j].z = gelu_exact(fmaf(fb.x, az, cz));
        h2r[j].w = gelu_exact(fmaf(fb.y, aw, cw));
    }

    const float* w2l = &w2s[l * 257];
    float acc[4] = {0.f, 0.f, 0.f, 0.f};
    #pragma unroll 8
    for (int mq = 0; mq < 64; mq++) {
        float w0  = w2l[4 * mq + 0];
        float w1_ = w2l[4 * mq + 1];
        float w2_ = w2l[4 * mq + 2];
        float w3_ = w2l[4 * mq + 3];
        #pragma unroll
        for (int j = 0; j < 4; j++) {
            acc[j] = fmaf(w0,  bcast_lane(h2r[j].x, mq), acc[j]);
            acc[j] = fmaf(w1_, bcast_lane(h2r[j].y, mq), acc[j]);
            acc[j] = fmaf(w2_, bcast_lane(h2r[j].z, mq), acc[j]);
            acc[j] = fmaf(w3_, bcast_lane(h2r[j].w, mq), acc[j]);
        }
    }

    float bias = b2[l];
    float so1 = 0.f, so2 = 0.f;
    #pragma unroll
    for (int j = 0; j < 4; j++) {
        acc[j] += bias;
        so1 += acc[j];
        so2 = fmaf(acc[j], acc[j], so2);
    }
    *(float4*)&oraw[((size_t)(b * CC) + l) * NN + n0] =
        make_float4(acc[0], acc[1], acc[2], acc[3]);

    so1 += __shfl_down(so1, 8, 16); so2 += __shfl_down(so2, 8, 16);
    so1 += __shfl_down(so1, 4, 16); so2 += __shfl_down(so2, 4, 16);
    so1 += __shfl_down(so1, 2, 16); so2 += __shfl_down(so2, 2, 16);
    so1 += __shfl_down(so1, 1, 16); so2 += __shfl_down(so2, 1, 16);
    if ((l & 15) == 0) { sA[w][l >> 4] = so1; sB[w][l >> 4] = so2; }
    __syncthreads();
    if (t < 8) {
        int is2 = t >> 2, gg = t & 3;
        float v = is2 ? (sB[0][gg] + sB[1][gg] + sB[2][gg] + sB[3][gg])
                      : (sA[0][gg] + sA[1][gg] + sA[2][gg] + sA[3][gg]);
        atomicAdd(&OpS[b * 8 + t], v);
    }
}

// ---------------- kernel D: final (gn3 + residual), grid 512 x 256 ----------------
__global__ void k_final(const float* __restrict__ oraw, const float* __restrict__ x,
                        const float* __restrict__ g2, const float* __restrict__ be2,
                        const float* __restrict__ OpS, float* __restrict__ out) {
    int t = threadIdx.x;
    int i4 = blockIdx.x * 256 + t;
    int base = i4 * 4;
    int b = base >> 18;
    int c = (base >> 12) & 63;
    int g = c >> 4;

    double s1 = (double)OpS[b * 8 + g];
    double s2 = (double)OpS[b * 8 + 4 + g];
    const double cntd = 16.0 * 4096.0;
    double mean_d = s1 / cntd;
    double var_d  = s2 / cntd - mean_d * mean_d;
    float mean = (float)mean_d;
    float rstd = rsqrtf((float)var_d + EPSF);
    float sc = rstd * g2[c];
    float ad = be2[c] - mean * sc;
    float4 o = ((const float4*)oraw)[i4];
    float4 xv = ((const float4*)x)[i4];
    float4 r;
    r.x = fmaf(o.x, sc, ad) + xv.x;
    r.y = fmaf(o.y, sc, ad) + xv.y;
    r.z = fmaf(o.z, sc, ad) + xv.z;
    r.w = fmaf(o.w, sc, ad) + xv.w;
    ((float4*)out)[i4] = r;
}

// ---------------- launch ----------------
extern "C" void kernel_launch(void* const* d_in, const int* in_sizes, int n_in,
                              void* d_out, int out_size, void* d_ws, size_t ws_size,
                              hipStream_t stream) {
    const float* x   = (const float*)d_in[0];
    const float* pos = (const float*)d_in[1];
    const float* w1  = (const float*)d_in[2];
    const float* b1  = (const float*)d_in[3];
    const float* g1  = (const float*)d_in[4];
    const float* be1 = (const float*)d_in[5];
    const float* wd  = (const float*)d_in[6];
    const float* gd  = (const float*)d_in[7];
    const float* bed = (const float*)d_in[8];
    const float* w2  = (const float*)d_in[9];
    const float* b2  = (const float*)d_in[10];
    const float* g2  = (const float*)d_in[11];
    const float* be2 = (const float*)d_in[12];
    float* out = (float*)d_out;

    char* wsb = (char*)d_ws;
    __half* hH    = (__half*)wsb;                    // 4 MB (fp16 h)
    __half* pH    = (__half*)(wsb + 8388608);        // 4 MB
    float*  oraw  = (float*)(wsb + 16777216);        // 2 MB
    int*    idxb  = (int*)(wsb + 18874368);          // 1 MB
    float2* Mp    = (float2*)(wsb + 20185088);       // 4 KB
    int*    cnt   = (int*)(wsb + 20189184);          // 32 KB (2 x 4096 ints)
    float*  GpS   = (float*)(wsb + 20221952);        // 64 B  (2 x 8 floats)
    float*  OpS   = (float*)(wsb + 20222016);        // 64 B  (2 x 8 floats)

    // zero the atomic accumulators (cnt + GpS + OpS are contiguous: 32768+64+64)
    hipMemsetAsync((void*)cnt, 0, 32896, stream);

    k_mlp1_ballq<<<2560, 256, 0, stream>>>(x, w1, b1, hH, Mp, pos, idxb, cnt);
    k_gn1t<<<512, 256, 0, stream>>>(hH, g1, be1, wd, Mp, pH, cnt, GpS);
    k_mlp2g<<<512, 256, 0, stream>>>(pH, idxb, GpS, w2, b2, gd, bed, oraw, OpS);
    k_final<<<512, 256, 0, stream>>>(oraw, x, g2, be2, OpS, out);
}

// Round 7
// 186.786 us; speedup vs baseline: 3.9429x; 1.0618x over previous
//
#include <hip/hip_runtime.h>
#include <hip/hip_fp16.h>
#include <math.h>

#define BB 2
#define CC 64
#define NN 4096
#define MM 256
#define KK 32
#define GG 4
#define EPSF 1e-5f

__device__ __forceinline__ float gelu_exact(float x) {
    return 0.5f * x * (1.0f + erff(x * 0.70710678118654752f));
}

__device__ __forceinline__ unsigned pkmax(unsigned a, unsigned b) {
    unsigned d;
    asm("v_pk_max_f16 %0, %1, %2" : "=v"(d) : "v"(a), "v"(b));
    return d;
}
__device__ __forceinline__ unsigned pkmin(unsigned a, unsigned b) {
    unsigned d;
    asm("v_pk_min_f16 %0, %1, %2" : "=v"(d) : "v"(a), "v"(b));
    return d;
}
__device__ __forceinline__ unsigned selpair(unsigned mx, unsigned mn, float g0, float g1) {
    unsigned lo = (g0 >= 0.f) ? (mx & 0x0000FFFFu) : (mn & 0x0000FFFFu);
    unsigned hi = (g1 >= 0.f) ? (mx & 0xFFFF0000u) : (mn & 0xFFFF0000u);
    return lo | hi;
}
__device__ __forceinline__ float bcast_lane(float v, int lane) {
    return __int_as_float(__builtin_amdgcn_readlane(__float_as_int(v), lane));
}

// Phase-2 selection replay: byte-identical semantics to the original ballq loop
// (j-ascending ballot order, same row/cnt writes, same early exit). All 64 lanes
// of the wave must call this (ballot participation).
__device__ __forceinline__ void ballq_select(unsigned long long mybits, int lane,
                                             int* __restrict__ row, int* __restrict__ cb) {
    int found = 0;
    int first = -1;
    for (int j = 0; j < 64 && found < KK; j++) {
        bool hit = (mybits >> j) & 1ULL;
        int m = j * 64 + lane;
        unsigned long long mask = __ballot(hit);
        if (first < 0 && mask) first = j * 64 + (__ffsll((long long)mask) - 1);
        unsigned long long lt = (lane == 0) ? 0ULL : (mask & ((1ULL << lane) - 1ULL));
        int posh = __popcll(lt);
        if (hit && (found + posh) < KK) {
            row[found + posh] = m;
            atomicAdd(&cb[m], 1);      // accepted occurrence
        }
        found += __popcll(mask);
        if (found > KK) found = KK;
    }
    if (lane < KK && lane >= found) row[lane] = first;
    if (lane == 0 && found < KK) atomicAdd(&cb[first], KK - found);  // duplicated fills
}

// ---------------- kernel A: mlp1 (blocks 0..511) UNION ballq+cnt (512..1023) ----------
// R6 post-mortem: 2x occupancy bought only 76->73us (VALUBusy 26%) -> not TLP-bound.
// VGPR=32 (launch_bounds 256,8) kept only ~4 of phase-1's pos loads in flight, and
// every query-wave streamed all 48KB of pos (400MB L1/L2 re-reads, msq recomputed
// 8192x/point). Fix: 4 QUERIES PER WAVE (pos traffic /4, msq shared across queries)
// + explicit ax[8]/ay[8]/az[8] register batches (24 loads in flight, static indices)
// + launch_bounds(256,4) so VGPR<=128 gives the batch room. ballq grid 2048->512.
// Phase 2 = original selection replay, 4x per wave (bit-exact; order preserved).
// Distance expression statements byte-identical (fma-contraction safety).
__global__ __launch_bounds__(256, 4)
void k_mlp1_ballq(const float* __restrict__ x, const float* __restrict__ w1,
                  const float* __restrict__ b1, __half* __restrict__ hH,
                  float2* __restrict__ Mp,
                  const float* __restrict__ pos, int* __restrict__ idxb,
                  int* __restrict__ cnt) {
    __shared__ __align__(16) float w1t[64 * 32 + 8];
    int t = threadIdx.x;

    if (blockIdx.x < 512) {
        // ---- mlp1 body (identical to R6) ----
        int bx = blockIdx.x;
        int nt = bx & 31, mt = (bx >> 5) & 7, b = bx >> 8;
        int n0 = nt * 128, m0 = mt * 32;

        {
            #pragma unroll
            for (int p = 0; p < 2; p++) {
                int idx = p * 256 + t;
                int m = idx >> 4, cq = idx & 15;
                float4 v = *(const float4*)&w1[(m0 + m) * CC + cq * 4];
                w1t[(cq * 4 + 0) * 32 + m] = v.x;
                w1t[(cq * 4 + 1) * 32 + m] = v.y;
                w1t[(cq * 4 + 2) * 32 + m] = v.z;
                w1t[(cq * 4 + 3) * 32 + m] = v.w;
            }
        }
        __syncthreads();

        int nq = t & 31;
        int mseg = t >> 5;
        const float* xb = &x[((size_t)(b * CC)) * NN + n0 + nq * 4];
        float o[4][4];
        #pragma unroll
        for (int i = 0; i < 4; i++)
            #pragma unroll
            for (int j = 0; j < 4; j++) o[i][j] = 0.f;

        #pragma unroll 4
        for (int c = 0; c < 64; c++) {
            float4 xv = *(const float4*)&xb[(size_t)c * NN];
            float4 wv = *(float4*)&w1t[c * 32 + mseg * 4];
            o[0][0] = fmaf(wv.x, xv.x, o[0][0]); o[0][1] = fmaf(wv.x, xv.y, o[0][1]);
            o[0][2] = fmaf(wv.x, xv.z, o[0][2]); o[0][3] = fmaf(wv.x, xv.w, o[0][3]);
            o[1][0] = fmaf(wv.y, xv.x, o[1][0]); o[1][1] = fmaf(wv.y, xv.y, o[1][1]);
            o[1][2] = fmaf(wv.y, xv.z, o[1][2]); o[1][3] = fmaf(wv.y, xv.w, o[1][3]);
            o[2][0] = fmaf(wv.z, xv.x, o[2][0]); o[2][1] = fmaf(wv.z, xv.y, o[2][1]);
            o[2][2] = fmaf(wv.z, xv.z, o[2][2]); o[2][3] = fmaf(wv.z, xv.w, o[2][3]);
            o[3][0] = fmaf(wv.w, xv.x, o[3][0]); o[3][1] = fmaf(wv.w, xv.y, o[3][1]);
            o[3][2] = fmaf(wv.w, xv.z, o[3][2]); o[3][3] = fmaf(wv.w, xv.w, o[3][3]);
        }

        float s1 = 0.f, s2 = 0.f;
        #pragma unroll
        for (int mi = 0; mi < 4; mi++) {
            int m = m0 + mseg * 4 + mi;
            float bv = b1[m];
            float4 r;
            r.x = o[mi][0] + bv; r.y = o[mi][1] + bv;
            r.z = o[mi][2] + bv; r.w = o[mi][3] + bv;
            __half2 hA = __float22half2_rn(make_float2(r.x, r.y));
            __half2 hB = __float22half2_rn(make_float2(r.z, r.w));
            uint2 st8;
            st8.x = *(unsigned*)&hA; st8.y = *(unsigned*)&hB;
            *(uint2*)((char*)hH + (((size_t)(b * MM + m)) * NN + n0 + nq * 4) * 2) = st8;
            s1 += r.x + r.y + r.z + r.w;
            s2 = fmaf(r.x, r.x, s2); s2 = fmaf(r.y, r.y, s2);
            s2 = fmaf(r.z, r.z, s2); s2 = fmaf(r.w, r.w, s2);
        }
        for (int off = 32; off; off >>= 1) {
            s1 += __shfl_down(s1, off, 64);
            s2 += __shfl_down(s2, off, 64);
        }
        __syncthreads();                   // all waves past w1t reads -> alias r1/r2 on it
        float* r1 = w1t + 64 * 32;
        float* r2 = r1 + 4;
        int w = t >> 6, l = t & 63;
        if (l == 0) { r1[w] = s1; r2[w] = s2; }
        __syncthreads();
        if (t == 0) {
            Mp[bx] = make_float2(r1[0] + r1[1] + r1[2] + r1[3],
                                 r2[0] + r2[1] + r2[2] + r2[3]);
        }
    } else {
        // ---- ballq: 4 queries per wave, batched phase-1, replayed phase-2 ----
        int bx = blockIdx.x - 512;            // 0..511
        int wv = t >> 6;
        int lane = t & 63;
        int qbase = (bx * 4 + wv) * 4;        // [0, 8192) step 4; same-batch quad
        int b = qbase >> 12;
        int nn0 = qbase & 4095;
        const float* px = pos + b * 3 * NN;
        const float* py = px + NN;
        const float* pz = py + NN;
        int* cb = cnt + b * NN;
        const float R2 = 0.04f;

        float qx0 = px[nn0 + 0], qy0 = py[nn0 + 0], qz0 = pz[nn0 + 0];
        float qx1 = px[nn0 + 1], qy1 = py[nn0 + 1], qz1 = pz[nn0 + 1];
        float qx2 = px[nn0 + 2], qy2 = py[nn0 + 2], qz2 = pz[nn0 + 2];
        float qx3 = px[nn0 + 3], qy3 = py[nn0 + 3], qz3 = pz[nn0 + 3];
        float qsq0 = qx0*qx0 + qy0*qy0 + qz0*qz0;
        float qsq1 = qx1*qx1 + qy1*qy1 + qz1*qz1;
        float qsq2 = qx2*qx2 + qy2*qy2 + qz2*qz2;
        float qsq3 = qx3*qx3 + qy3*qy3 + qz3*qz3;

        unsigned long long bits0 = 0ULL, bits1 = 0ULL, bits2 = 0ULL, bits3 = 0ULL;

        // phase 1: 8 batches of 8 points; 24 loads in flight per batch; msq shared
        // across the 4 queries. Distance statements identical to the original tree.
        #pragma unroll 1
        for (int jb = 0; jb < 8; jb++) {
            float ax[8], ay[8], az[8];
            #pragma unroll
            for (int u = 0; u < 8; u++) {
                int m = (jb * 8 + u) * 64 + lane;
                ax[u] = px[m]; ay[u] = py[m]; az[u] = pz[m];
            }
            #pragma unroll
            for (int u = 0; u < 8; u++) {
                int j = jb * 8 + u;
                float msq = ax[u]*ax[u] + ay[u]*ay[u] + az[u]*az[u];
                float dot0 = qx0*ax[u] + qy0*ay[u] + qz0*az[u];
                float d0 = qsq0 + msq - 2.0f * dot0;
                if (!(d0 > R2)) bits0 |= (1ULL << j);
                float dot1 = qx1*ax[u] + qy1*ay[u] + qz1*az[u];
                float d1 = qsq1 + msq - 2.0f * dot1;
                if (!(d1 > R2)) bits1 |= (1ULL << j);
                float dot2 = qx2*ax[u] + qy2*ay[u] + qz2*az[u];
                float d2 = qsq2 + msq - 2.0f * dot2;
                if (!(d2 > R2)) bits2 |= (1ULL << j);
                float dot3 = qx3*ax[u] + qy3*ay[u] + qz3*az[u];
                float d3 = qsq3 + msq - 2.0f * dot3;
                if (!(d3 > R2)) bits3 |= (1ULL << j);
            }
        }

        // phase 2: per-query selection replay (bit-exact vs original)
        ballq_select(bits0, lane, idxb + ((size_t)(b * NN) + nn0 + 0) * KK, cb);
        ballq_select(bits1, lane, idxb + ((size_t)(b * NN) + nn0 + 1) * KK, cb);
        ballq_select(bits2, lane, idxb + ((size_t)(b * NN) + nn0 + 2) * KK, cb);
        ballq_select(bits3, lane, idxb + ((size_t)(b * NN) + nn0 + 3) * KK, cb);
    }
}

// ---------------- kernel B: gn1t + GN2-stat accumulation via cnt ----------------
// grid 512, block 256. Identical gn1t arithmetic; each block weights its 64 columns'
// group-sums by cnt[j] and atomically accumulates into GpS[b*8 + {g, 4+g}].
__global__ void k_gn1t(const __half* __restrict__ hH, const float* __restrict__ g1,
                       const float* __restrict__ be1, const float* __restrict__ wd,
                       const float2* __restrict__ Mp, __half* __restrict__ pH,
                       const int* __restrict__ cnt, float* __restrict__ GpS) {
    __shared__ float tile[64 * 65];
    __shared__ float mv[2];
    __shared__ float sAcc1, sAcc2;
    int t = threadIdx.x;

    int id = blockIdx.x;
    int n0 = (id & 63) * 64;
    int g  = (id >> 6) & 3;
    int b  = id >> 8;
    int m0 = g * 64;

    if (t == 0) { sAcc1 = 0.f; sAcc2 = 0.f; }
    if (t < 64) {
        float2 p2 = Mp[b * 256 + g * 64 + t];
        float s1 = p2.x, s2 = p2.y;
        for (int off = 32; off; off >>= 1) {
            s1 += __shfl_down(s1, off, 64);
            s2 += __shfl_down(s2, off, 64);
        }
        if (t == 0) {
            const double cntd = 64.0 * 4096.0;
            double md = (double)s1 / cntd;
            double vd = (double)s2 / cntd - md * md;
            mv[0] = (float)md;
            mv[1] = rsqrtf((float)vd + EPSF);
        }
    }
    __syncthreads();
    float mean = mv[0], rstd = mv[1];

    int nq = t & 15, mr = t >> 4;
    #pragma unroll
    for (int pp = 0; pp < 4; pp++) {
        int row = pp * 16 + mr;
        int m = m0 + row;
        float a = rstd * g1[m];
        float cc2 = be1[m] - mean * a;
        float wdm = wd[m];
        uint2 raw = *(const uint2*)((const char*)hH +
                     (((size_t)(b * MM + m)) * NN + n0 + nq * 4) * 2);
        float2 fa = __half22float2(*(__half2*)&raw.x);
        float2 fb = __half22float2(*(__half2*)&raw.y);
        tile[row * 65 + nq * 4 + 0] = gelu_exact(fmaf(fa.x, a, cc2)) * wdm;
        tile[row * 65 + nq * 4 + 1] = gelu_exact(fmaf(fa.y, a, cc2)) * wdm;
        tile[row * 65 + nq * 4 + 2] = gelu_exact(fmaf(fb.x, a, cc2)) * wdm;
        tile[row * 65 + nq * 4 + 3] = gelu_exact(fmaf(fb.y, a, cc2)) * wdm;
    }
    __syncthreads();
    #pragma unroll
    for (int pp = 0; pp < 4; pp++) {
        int id2 = pp * 256 + t;
        int nl = id2 >> 4, mq = id2 & 15;
        float a0 = tile[(mq * 4 + 0) * 65 + nl];
        float a1 = tile[(mq * 4 + 1) * 65 + nl];
        float a2 = tile[(mq * 4 + 2) * 65 + nl];
        float a3 = tile[(mq * 4 + 3) * 65 + nl];
        __half2 hA = __float22half2_rn(make_float2(a0, a1));
        __half2 hB = __float22half2_rn(make_float2(a2, a3));
        uint2 st8;
        st8.x = *(unsigned*)&hA; st8.y = *(unsigned*)&hB;
        *(uint2*)((char*)pH + ((((size_t)(b * NN) + n0 + nl)) << 9) + (m0 + mq * 4) * 2) = st8;
        float2 fa = __half22float2(hA);
        float2 fb = __half22float2(hB);
        float t1 = fa.x + fa.y + fb.x + fb.y;
        float t2 = fa.x * fa.x + fa.y * fa.y + fb.x * fb.x + fb.y * fb.y;
        #pragma unroll
        for (int off = 8; off; off >>= 1) {
            t1 += __shfl_down(t1, off, 16);
            t2 += __shfl_down(t2, off, 16);
        }
        if ((t & 15) == 0) {
            float cw = (float)cnt[b * NN + n0 + nl];
            atomicAdd(&sAcc1, cw * t1);
            atomicAdd(&sAcc2, cw * t2);
        }
    }
    __syncthreads();
    if (t == 0) {
        atomicAdd(&GpS[b * 8 + g],     sAcc1);
        atomicAdd(&GpS[b * 8 + 4 + g], sAcc2);
    }
}

// ---------------- kernel C: mlp2g (fused gather + GN2 + gelu + w2 matmul) ----------
// grid 512 (2 blocks/CU, LDS ~74KB), 4 cols/wave; XCD batch split. GN2 stats from
// GpS (8 floats/batch); GN3 partials to OpS via 8 atomicAdds/block.
__global__ __launch_bounds__(256, 2)
void k_mlp2g(const __half* __restrict__ pH, const int* __restrict__ idxb,
             const float* __restrict__ GpS, const float* __restrict__ w2,
             const float* __restrict__ b2, const float* __restrict__ gd,
             const float* __restrict__ bed, float* __restrict__ oraw,
             float* __restrict__ OpS) {
    __shared__ float w2s[64 * 257];
    __shared__ uint4 phs4[4][4][32];   // [wave][col][32*uint4 = 256 half] per-wave scratch
    __shared__ float sA[4][4], sB[4][4];

    int t = threadIdx.x;
    int w = t >> 6, l = t & 63;
    int q = blockIdx.x;
    int b = ((q & 7) < 4) ? 0 : 1;
    int local = (q >> 3) * 4 + (q & 3);        // [0, 256), unique per batch
    int n0 = local * 16 + w * 4;

    #pragma unroll
    for (int p = 0; p < 16; p++) {
        int i = p * 256 + t;
        int c = i >> 6, mq = i & 63;
        float4 v = ((const float4*)w2)[i];
        float* dst = &w2s[c * 257 + mq * 4];
        dst[0] = v.x; dst[1] = v.y; dst[2] = v.z; dst[3] = v.w;
    }
    __syncthreads();

    int g = l >> 4;
    double s1 = (double)GpS[b * 8 + g];
    double s2 = (double)GpS[b * 8 + 4 + g];
    const double cnt2 = 64.0 * 4096.0 * 32.0;
    double m_ = s1 / cnt2;
    double v_ = s2 / cnt2 - m_ * m_;
    float mean = (float)m_;
    float rstd = rsqrtf((float)v_ + EPSF);
    float4 gd4  = ((const float4*)gd)[l];
    float4 bed4 = ((const float4*)bed)[l];
    float ax = rstd * gd4.x, ay = rstd * gd4.y, az = rstd * gd4.z, aw = rstd * gd4.w;
    float cx = bed4.x - mean * ax, cy = bed4.y - mean * ay;
    float cz = bed4.z - mean * az, cw = bed4.w - mean * aw;

    // ---- fused gather for this wave's 4 columns (bit-identical reduction) ----
    {
        int hh = l >> 5, cl = l & 31;
        const char* pb = (const char*)(pH + (size_t)b * NN * 256);
        int laneoff = cl * 16;
        const float4* g4 = (const float4*)gd;
        float4 gA = g4[cl * 2], gB = g4[cl * 2 + 1];
        #pragma unroll
        for (int p = 0; p < 4; p++) {
            int myidx = idxb[((size_t)(b * NN) + n0 + p) * KK + cl];
            unsigned vmax0 = 0xFC00FC00u, vmax1 = 0xFC00FC00u, vmax2 = 0xFC00FC00u, vmax3 = 0xFC00FC00u;
            unsigned vmin0 = 0x7C007C00u, vmin1 = 0x7C007C00u, vmin2 = 0x7C007C00u, vmin3 = 0x7C007C00u;
            #pragma unroll
            for (int kb = 0; kb < 4; kb++) {
                int jj[4];
                #pragma unroll
                for (int u = 0; u < 4; u++) {
                    int k = kb * 4 + u;
                    int ja = __shfl(myidx, 2 * k, 64);
                    int jb = __shfl(myidx, 2 * k + 1, 64);
                    jj[u] = hh ? jb : ja;
                }
                uint4 r[4];
                #pragma unroll
                for (int u = 0; u < 4; u++)
                    r[u] = *(const uint4*)(pb + (((size_t)jj[u]) << 9) + laneoff);
                #pragma unroll
                for (int u = 0; u < 4; u++) {
                    vmax0 = pkmax(vmax0, r[u].x); vmin0 = pkmin(vmin0, r[u].x);
                    vmax1 = pkmax(vmax1, r[u].y); vmin1 = pkmin(vmin1, r[u].y);
                    vmax2 = pkmax(vmax2, r[u].z); vmin2 = pkmin(vmin2, r[u].z);
                    vmax3 = pkmax(vmax3, r[u].w); vmin3 = pkmin(vmin3, r[u].w);
                }
            }
            vmax0 = pkmax(vmax0, (unsigned)__shfl_xor((int)vmax0, 32, 64));
            vmax1 = pkmax(vmax1, (unsigned)__shfl_xor((int)vmax1, 32, 64));
            vmax2 = pkmax(vmax2, (unsigned)__shfl_xor((int)vmax2, 32, 64));
            vmax3 = pkmax(vmax3, (unsigned)__shfl_xor((int)vmax3, 32, 64));
            vmin0 = pkmin(vmin0, (unsigned)__shfl_xor((int)vmin0, 32, 64));
            vmin1 = pkmin(vmin1, (unsigned)__shfl_xor((int)vmin1, 32, 64));
            vmin2 = pkmin(vmin2, (unsigned)__shfl_xor((int)vmin2, 32, 64));
            vmin3 = pkmin(vmin3, (unsigned)__shfl_xor((int)vmin3, 32, 64));

            if (hh == 0) {
                uint4 o4;
                o4.x = selpair(vmax0, vmin0, gA.x, gA.y);
                o4.y = selpair(vmax1, vmin1, gA.z, gA.w);
                o4.z = selpair(vmax2, vmin2, gB.x, gB.y);
                o4.w = selpair(vmax3, vmin3, gB.z, gB.w);
                phs4[w][p][cl] = o4;   // per-wave slot: same-wave RAW, no barrier
            }
        }
    }

    // ---- GN + gelu on the gathered columns ----
    float4 h2r[4];
    #pragma unroll
    for (int j = 0; j < 4; j++) {
        const uint2* pr = (const uint2*)&phs4[w][j][0];
        uint2 raw = pr[l];
        float2 fa = __half22float2(*(__half2*)&raw.x);
        float2 fb = __half22float2(*(__half2*)&raw.y);
        h2r[j].x = gelu_exact(fmaf(fa.x, ax, cx));
        h2r[j].y = gelu_exact(fmaf(fa.y, ay, cy));
        h2r[j].z = gelu_exact(fmaf(fb.x, az, cz));
        h2r[j].w = gelu_exact(fmaf(fb.y, aw, cw));
    }

    const float* w2l = &w2s[l * 257];
    float acc[4] = {0.f, 0.f, 0.f, 0.f};
    #pragma unroll 8
    for (int mq = 0; mq < 64; mq++) {
        float w0  = w2l[4 * mq + 0];
        float w1_ = w2l[4 * mq + 1];
        float w2_ = w2l[4 * mq + 2];
        float w3_ = w2l[4 * mq + 3];
        #pragma unroll
        for (int j = 0; j < 4; j++) {
            acc[j] = fmaf(w0,  bcast_lane(h2r[j].x, mq), acc[j]);
            acc[j] = fmaf(w1_, bcast_lane(h2r[j].y, mq), acc[j]);
            acc[j] = fmaf(w2_, bcast_lane(h2r[j].z, mq), acc[j]);
            acc[j] = fmaf(w3_, bcast_lane(h2r[j].w, mq), acc[j]);
        }
    }

    float bias = b2[l];
    float so1 = 0.f, so2 = 0.f;
    #pragma unroll
    for (int j = 0; j < 4; j++) {
        acc[j] += bias;
        so1 += acc[j];
        so2 = fmaf(acc[j], acc[j], so2);
    }
    *(float4*)&oraw[((size_t)(b * CC) + l) * NN + n0] =
        make_float4(acc[0], acc[1], acc[2], acc[3]);

    so1 += __shfl_down(so1, 8, 16); so2 += __shfl_down(so2, 8, 16);
    so1 += __shfl_down(so1, 4, 16); so2 += __shfl_down(so2, 4, 16);
    so1 += __shfl_down(so1, 2, 16); so2 += __shfl_down(so2, 2, 16);
    so1 += __shfl_down(so1, 1, 16); so2 += __shfl_down(so2, 1, 16);
    if ((l & 15) == 0) { sA[w][l >> 4] = so1; sB[w][l >> 4] = so2; }
    __syncthreads();
    if (t < 8) {
        int is2 = t >> 2, gg = t & 3;
        float v = is2 ? (sB[0][gg] + sB[1][gg] + sB[2][gg] + sB[3][gg])
                      : (sA[0][gg] + sA[1][gg] + sA[2][gg] + sA[3][gg]);
        atomicAdd(&OpS[b * 8 + t], v);
    }
}

// ---------------- kernel D: final (gn3 + residual), grid 512 x 256 ----------------
__global__ void k_final(const float* __restrict__ oraw, const float* __restrict__ x,
                        const float* __restrict__ g2, const float* __restrict__ be2,
                        const float* __restrict__ OpS, float* __restrict__ out) {
    int t = threadIdx.x;
    int i4 = blockIdx.x * 256 + t;
    int base = i4 * 4;
    int b = base >> 18;
    int c = (base >> 12) & 63;
    int g = c >> 4;

    double s1 = (double)OpS[b * 8 + g];
    double s2 = (double)OpS[b * 8 + 4 + g];
    const double cntd = 16.0 * 4096.0;
    double mean_d = s1 / cntd;
    double var_d  = s2 / cntd - mean_d * mean_d;
    float mean = (float)mean_d;
    float rstd = rsqrtf((float)var_d + EPSF);
    float sc = rstd * g2[c];
    float ad = be2[c] - mean * sc;
    float4 o = ((const float4*)oraw)[i4];
    float4 xv = ((const float4*)x)[i4];
    float4 r;
    r.x = fmaf(o.x, sc, ad) + xv.x;
    r.y = fmaf(o.y, sc, ad) + xv.y;
    r.z = fmaf(o.z, sc, ad) + xv.z;
    r.w = fmaf(o.w, sc, ad) + xv.w;
    ((float4*)out)[i4] = r;
}

// ---------------- launch ----------------
extern "C" void kernel_launch(void* const* d_in, const int* in_sizes, int n_in,
                              void* d_out, int out_size, void* d_ws, size_t ws_size,
                              hipStream_t stream) {
    const float* x   = (const float*)d_in[0];
    const float* pos = (const float*)d_in[1];
    const float* w1  = (const float*)d_in[2];
    const float* b1  = (const float*)d_in[3];
    const float* g1  = (const float*)d_in[4];
    const float* be1 = (const float*)d_in[5];
    const float* wd  = (const float*)d_in[6];
    const float* gd  = (const float*)d_in[7];
    const float* bed = (const float*)d_in[8];
    const float* w2  = (const float*)d_in[9];
    const float* b2  = (const float*)d_in[10];
    const float* g2  = (const float*)d_in[11];
    const float* be2 = (const float*)d_in[12];
    float* out = (float*)d_out;

    char* wsb = (char*)d_ws;
    __half* hH    = (__half*)wsb;                    // 4 MB (fp16 h)
    __half* pH    = (__half*)(wsb + 8388608);        // 4 MB
    float*  oraw  = (float*)(wsb + 16777216);        // 2 MB
    int*    idxb  = (int*)(wsb + 18874368);          // 1 MB
    float2* Mp    = (float2*)(wsb + 20185088);       // 4 KB
    int*    cnt   = (int*)(wsb + 20189184);          // 32 KB (2 x 4096 ints)
    float*  GpS   = (float*)(wsb + 20221952);        // 64 B  (2 x 8 floats)
    float*  OpS   = (float*)(wsb + 20222016);        // 64 B  (2 x 8 floats)

    // zero the atomic accumulators (cnt + GpS + OpS are contiguous: 32768+64+64)
    hipMemsetAsync((void*)cnt, 0, 32896, stream);

    k_mlp1_ballq<<<1024, 256, 0, stream>>>(x, w1, b1, hH, Mp, pos, idxb, cnt);
    k_gn1t<<<512, 256, 0, stream>>>(hH, g1, be1, wd, Mp, pH, cnt, GpS);
    k_mlp2g<<<512, 256, 0, stream>>>(pH, idxb, GpS, w2, b2, gd, bed, oraw, OpS);
    k_final<<<512, 256, 0, stream>>>(oraw, x, g2, be2, OpS, out);
}

// Round 8
// 145.357 us; speedup vs baseline: 5.0667x; 1.2850x over previous
//
#include <hip/hip_runtime.h>
#include <hip/hip_fp16.h>
#include <math.h>

#define BB 2
#define CC 64
#define NN 4096
#define MM 256
#define KK 32
#define GG 4
#define EPSF 1e-5f

__device__ __forceinline__ float gelu_exact(float x) {
    return 0.5f * x * (1.0f + erff(x * 0.70710678118654752f));
}

__device__ __forceinline__ unsigned pkmax(unsigned a, unsigned b) {
    unsigned d;
    asm("v_pk_max_f16 %0, %1, %2" : "=v"(d) : "v"(a), "v"(b));
    return d;
}
__device__ __forceinline__ unsigned pkmin(unsigned a, unsigned b) {
    unsigned d;
    asm("v_pk_min_f16 %0, %1, %2" : "=v"(d) : "v"(a), "v"(b));
    return d;
}
__device__ __forceinline__ unsigned selpair(unsigned mx, unsigned mn, float g0, float g1) {
    unsigned lo = (g0 >= 0.f) ? (mx & 0x0000FFFFu) : (mn & 0x0000FFFFu);
    unsigned hi = (g1 >= 0.f) ? (mx & 0xFFFF0000u) : (mn & 0xFFFF0000u);
    return lo | hi;
}
__device__ __forceinline__ float bcast_lane(float v, int lane) {
    return __int_as_float(__builtin_amdgcn_readlane(__float_as_int(v), lane));
}

// ---------------- mlp1: h = w1 @ x + b1 (fp16 out), per-block stats partials ----------
// grid 512 = B(2) x MT(8 tiles of 32 m) x NT(32 tiles of 128 n), block 256
__global__ void k_mlp1(const float* __restrict__ x, const float* __restrict__ w1,
                       const float* __restrict__ b1, __half* __restrict__ hH,
                       float2* __restrict__ Mp) {
    __shared__ float xs[64 * 128];
    __shared__ float w1t[64 * 32];
    __shared__ float r1[4], r2[4];

    int bx = blockIdx.x;
    int nt = bx & 31, mt = (bx >> 5) & 7, b = bx >> 8;
    int n0 = nt * 128, m0 = mt * 32;
    int t = threadIdx.x;

    {
        int nq = t & 31, ch = t >> 5;
        #pragma unroll
        for (int p = 0; p < 8; p++) {
            int c = p * 8 + ch;
            float4 v = *(const float4*)&x[((size_t)(b * CC + c)) * NN + n0 + nq * 4];
            *(float4*)&xs[c * 128 + nq * 4] = v;
        }
    }
    {
        #pragma unroll
        for (int p = 0; p < 2; p++) {
            int idx = p * 256 + t;
            int m = idx >> 4, cq = idx & 15;
            float4 v = *(const float4*)&w1[(m0 + m) * CC + cq * 4];
            w1t[(cq * 4 + 0) * 32 + m] = v.x;
            w1t[(cq * 4 + 1) * 32 + m] = v.y;
            w1t[(cq * 4 + 2) * 32 + m] = v.z;
            w1t[(cq * 4 + 3) * 32 + m] = v.w;
        }
    }
    __syncthreads();

    int nq = t & 31;
    int mseg = t >> 5;
    float o[4][4];
    #pragma unroll
    for (int i = 0; i < 4; i++)
        #pragma unroll
        for (int j = 0; j < 4; j++) o[i][j] = 0.f;

    for (int c = 0; c < 64; c++) {
        float4 xv = *(float4*)&xs[c * 128 + nq * 4];
        float4 wv = *(float4*)&w1t[c * 32 + mseg * 4];
        o[0][0] = fmaf(wv.x, xv.x, o[0][0]); o[0][1] = fmaf(wv.x, xv.y, o[0][1]);
        o[0][2] = fmaf(wv.x, xv.z, o[0][2]); o[0][3] = fmaf(wv.x, xv.w, o[0][3]);
        o[1][0] = fmaf(wv.y, xv.x, o[1][0]); o[1][1] = fmaf(wv.y, xv.y, o[1][1]);
        o[1][2] = fmaf(wv.y, xv.z, o[1][2]); o[1][3] = fmaf(wv.y, xv.w, o[1][3]);
        o[2][0] = fmaf(wv.z, xv.x, o[2][0]); o[2][1] = fmaf(wv.z, xv.y, o[2][1]);
        o[2][2] = fmaf(wv.z, xv.z, o[2][2]); o[2][3] = fmaf(wv.z, xv.w, o[2][3]);
        o[3][0] = fmaf(wv.w, xv.x, o[3][0]); o[3][1] = fmaf(wv.w, xv.y, o[3][1]);
        o[3][2] = fmaf(wv.w, xv.z, o[3][2]); o[3][3] = fmaf(wv.w, xv.w, o[3][3]);
    }

    float s1 = 0.f, s2 = 0.f;
    #pragma unroll
    for (int mi = 0; mi < 4; mi++) {
        int m = m0 + mseg * 4 + mi;
        float bv = b1[m];
        float4 r;
        r.x = o[mi][0] + bv; r.y = o[mi][1] + bv;
        r.z = o[mi][2] + bv; r.w = o[mi][3] + bv;
        __half2 hA = __float22half2_rn(make_float2(r.x, r.y));
        __half2 hB = __float22half2_rn(make_float2(r.z, r.w));
        uint2 st8;
        st8.x = *(unsigned*)&hA; st8.y = *(unsigned*)&hB;
        *(uint2*)((char*)hH + (((size_t)(b * MM + m)) * NN + n0 + nq * 4) * 2) = st8;
        s1 += r.x + r.y + r.z + r.w;
        s2 = fmaf(r.x, r.x, s2); s2 = fmaf(r.y, r.y, s2);
        s2 = fmaf(r.z, r.z, s2); s2 = fmaf(r.w, r.w, s2);
    }
    for (int off = 32; off; off >>= 1) {
        s1 += __shfl_down(s1, off, 64);
        s2 += __shfl_down(s2, off, 64);
    }
    int w = t >> 6, l = t & 63;
    if (l == 0) { r1[w] = s1; r2[w] = s2; }
    __syncthreads();
    if (t == 0) {
        Mp[bx] = make_float2(r1[0] + r1[1] + r1[2] + r1[3],
                             r2[0] + r2[1] + r2[2] + r2[3]);
    }
}

// ---------------- union kernel: gn1t (blocks 0..511) + ballq (blocks 512..2559) ----------
// EXACT round-0 structure (145.3us baseline). ONLY change: ballq body is the
// two-phase bitmask form -- phase 1 evaluates all 64 point-groups independently
// (loads pipeline deep, no loop-carried state), phase 2 replays the ORIGINAL
// selection loop bit-exactly over register bits (same j order, same row writes,
// same early exit, same fill). ballq stays co-scheduled with gn1t, whose
// memory/VALU work hides ballq's stalls (the R4-R7 standalone-ballq lesson).
// fma-contraction safety: distance expression statements byte-identical.
__global__ void k_gn1t_ballq(const __half* __restrict__ hH, const float* __restrict__ g1,
                             const float* __restrict__ be1, const float* __restrict__ wd,
                             const float2* __restrict__ Mp, __half* __restrict__ pH,
                             float* __restrict__ R,
                             const float* __restrict__ pos, int* __restrict__ idx) {
    __shared__ float tile[64 * 65];
    __shared__ float mv[2];
    int t = threadIdx.x;

    if (blockIdx.x < 512) {
        // ---- gn1t body ----
        int id = blockIdx.x;
        int n0 = (id & 63) * 64;
        int g  = (id >> 6) & 3;
        int b  = id >> 8;
        int m0 = g * 64;

        if (t < 64) {
            float2 p2 = Mp[b * 256 + g * 64 + t];
            float s1 = p2.x, s2 = p2.y;
            for (int off = 32; off; off >>= 1) {
                s1 += __shfl_down(s1, off, 64);
                s2 += __shfl_down(s2, off, 64);
            }
            if (t == 0) {
                const double cnt = 64.0 * 4096.0;
                double md = (double)s1 / cnt;
                double vd = (double)s2 / cnt - md * md;
                mv[0] = (float)md;
                mv[1] = rsqrtf((float)vd + EPSF);
            }
        }
        __syncthreads();
        float mean = mv[0], rstd = mv[1];

        int nq = t & 15, mr = t >> 4;
        #pragma unroll
        for (int pp = 0; pp < 4; pp++) {
            int row = pp * 16 + mr;
            int m = m0 + row;
            float a = rstd * g1[m];
            float cc2 = be1[m] - mean * a;
            float wdm = wd[m];
            uint2 raw = *(const uint2*)((const char*)hH +
                         (((size_t)(b * MM + m)) * NN + n0 + nq * 4) * 2);
            float2 fa = __half22float2(*(__half2*)&raw.x);
            float2 fb = __half22float2(*(__half2*)&raw.y);
            tile[row * 65 + nq * 4 + 0] = gelu_exact(fmaf(fa.x, a, cc2)) * wdm;
            tile[row * 65 + nq * 4 + 1] = gelu_exact(fmaf(fa.y, a, cc2)) * wdm;
            tile[row * 65 + nq * 4 + 2] = gelu_exact(fmaf(fb.x, a, cc2)) * wdm;
            tile[row * 65 + nq * 4 + 3] = gelu_exact(fmaf(fb.y, a, cc2)) * wdm;
        }
        __syncthreads();
        #pragma unroll
        for (int pp = 0; pp < 4; pp++) {
            int id2 = pp * 256 + t;
            int nl = id2 >> 4, mq = id2 & 15;
            float a0 = tile[(mq * 4 + 0) * 65 + nl];
            float a1 = tile[(mq * 4 + 1) * 65 + nl];
            float a2 = tile[(mq * 4 + 2) * 65 + nl];
            float a3 = tile[(mq * 4 + 3) * 65 + nl];
            __half2 hA = __float22half2_rn(make_float2(a0, a1));
            __half2 hB = __float22half2_rn(make_float2(a2, a3));
            uint2 st8;
            st8.x = *(unsigned*)&hA; st8.y = *(unsigned*)&hB;
            *(uint2*)((char*)pH + ((((size_t)(b * NN) + n0 + nl)) << 9) + (m0 + mq * 4) * 2) = st8;
            float2 fa = __half22float2(hA);
            float2 fb = __half22float2(hB);
            float t1 = fa.x + fa.y + fb.x + fb.y;
            float t2 = fa.x * fa.x + fa.y * fa.y + fb.x * fb.x + fb.y * fb.y;
            #pragma unroll
            for (int off = 8; off; off >>= 1) {
                t1 += __shfl_down(t1, off, 16);
                t2 += __shfl_down(t2, off, 16);
            }
            if ((t & 15) == 0) {
                float* rr = &R[((size_t)(b * NN) + n0 + nl) * 8];
                rr[g]     = t1;
                rr[4 + g] = t2;
            }
        }
    } else {
        // ---- ballq body (bx = blockIdx.x - 512), two-phase bitmask form ----
        int bx = blockIdx.x - 512;
        int wid  = bx * 4 + (threadIdx.x >> 6);
        int lane = threadIdx.x & 63;
        int b = wid >> 12;
        int n = wid & 4095;
        const float* px = pos + b * 3 * NN;
        const float* py = px + NN;
        const float* pz = py + NN;
        float qx = px[n], qy = py[n], qz = pz[n];
        float qsq = qx*qx + qy*qy + qz*qz;
        int* row = idx + (b * NN + n) * KK;
        const float R2 = 0.04f;

        // phase 1: independent hit evaluation, per-lane bit j = hit(point j*64+lane)
        unsigned long long mybits = 0ULL;
        #pragma unroll 16
        for (int j = 0; j < 64; j++) {
            int m = j * 64 + lane;
            float ax = px[m], ay = py[m], az = pz[m];
            float msq = ax*ax + ay*ay + az*az;
            float dot = qx*ax + qy*ay + qz*az;
            float d = qsq + msq - 2.0f * dot;
            bool hit = !(d > R2);
            if (hit) mybits |= (1ULL << j);
        }

        // phase 2: original selection loop over register bits (bit-identical order)
        int found = 0;
        int first = -1;
        for (int j = 0; j < 64 && found < KK; j++) {
            bool hit = (mybits >> j) & 1ULL;
            int m = j * 64 + lane;
            unsigned long long mask = __ballot(hit);
            if (first < 0 && mask) first = j * 64 + (__ffsll((long long)mask) - 1);
            unsigned long long lt = (lane == 0) ? 0ULL : (mask & ((1ULL << lane) - 1ULL));
            int posh = __popcll(lt);
            if (hit && (found + posh) < KK) row[found + posh] = m;
            found += __popcll(mask);
            if (found > KK) found = KK;
        }
        if (lane < KK && lane >= found) row[lane] = first;
    }
}

// ---------------- union kernel: qgather (blocks 0..2047) + gstats (2048..2303) ----------
// XCD-aware batch split (blockIdx%8 selects batch). Gather loop batched 4 loads at a
// time (explicit uint4 r[4]) for load ILP. Max/min accumulation is order-independent,
// so the reassociated reduction is bit-exact vs the serial form.
__global__ __launch_bounds__(256)
void k_qgather_gstats(const __half* __restrict__ pH, const int* __restrict__ idx,
                      const float* __restrict__ R, const float* __restrict__ gd,
                      __half* __restrict__ pselH, float* __restrict__ Gp) {
    __shared__ float sAcc[8][8];
    int t = threadIdx.x;

    if (blockIdx.x < 2048) {
        int q = blockIdx.x;
        int b = ((q & 7) < 4) ? 0 : 1;
        int local = (q >> 3) * 4 + (q & 3);     // [0, 1024), unique per batch
        int w = t >> 6, l = t & 63;
        int gn = b * NN + local * 4 + w;

        int hh = l >> 5, cl = l & 31;
        int myidx = idx[gn * KK + cl];
        const char* pb = (const char*)(pH + (size_t)b * NN * 256);
        int laneoff = cl * 16;

        unsigned vmax0 = 0xFC00FC00u, vmax1 = 0xFC00FC00u, vmax2 = 0xFC00FC00u, vmax3 = 0xFC00FC00u;
        unsigned vmin0 = 0x7C007C00u, vmin1 = 0x7C007C00u, vmin2 = 0x7C007C00u, vmin3 = 0x7C007C00u;

        #pragma unroll
        for (int kb = 0; kb < 4; kb++) {
            int jj[4];
            #pragma unroll
            for (int u = 0; u < 4; u++) {
                int k = kb * 4 + u;
                int ja = __shfl(myidx, 2 * k, 64);
                int jb = __shfl(myidx, 2 * k + 1, 64);
                jj[u] = hh ? jb : ja;
            }
            uint4 r[4];
            #pragma unroll
            for (int u = 0; u < 4; u++)
                r[u] = *(const uint4*)(pb + (((size_t)jj[u]) << 9) + laneoff);
            #pragma unroll
            for (int u = 0; u < 4; u++) {
                vmax0 = pkmax(vmax0, r[u].x); vmin0 = pkmin(vmin0, r[u].x);
                vmax1 = pkmax(vmax1, r[u].y); vmin1 = pkmin(vmin1, r[u].y);
                vmax2 = pkmax(vmax2, r[u].z); vmin2 = pkmin(vmin2, r[u].z);
                vmax3 = pkmax(vmax3, r[u].w); vmin3 = pkmin(vmin3, r[u].w);
            }
        }
        vmax0 = pkmax(vmax0, (unsigned)__shfl_xor((int)vmax0, 32, 64));
        vmax1 = pkmax(vmax1, (unsigned)__shfl_xor((int)vmax1, 32, 64));
        vmax2 = pkmax(vmax2, (unsigned)__shfl_xor((int)vmax2, 32, 64));
        vmax3 = pkmax(vmax3, (unsigned)__shfl_xor((int)vmax3, 32, 64));
        vmin0 = pkmin(vmin0, (unsigned)__shfl_xor((int)vmin0, 32, 64));
        vmin1 = pkmin(vmin1, (unsigned)__shfl_xor((int)vmin1, 32, 64));
        vmin2 = pkmin(vmin2, (unsigned)__shfl_xor((int)vmin2, 32, 64));
        vmin3 = pkmin(vmin3, (unsigned)__shfl_xor((int)vmin3, 32, 64));

        if (hh == 0) {
            const float4* g4 = (const float4*)gd;
            float4 gA = g4[cl * 2], gB = g4[cl * 2 + 1];
            uint4 o4;
            o4.x = selpair(vmax0, vmin0, gA.x, gA.y);
            o4.y = selpair(vmax1, vmin1, gA.z, gA.w);
            o4.z = selpair(vmax2, vmin2, gB.x, gB.y);
            o4.w = selpair(vmax3, vmin3, gB.z, gB.w);
            *(uint4*)((char*)pselH + (((size_t)gn) << 9) + laneoff) = o4;
        }
    } else {
        int bid = blockIdx.x - 2048;
        int hw = t >> 5, cl = t & 31;
        int pbase = bid * 32;
        int b = pbase >> 12;
        float s[8];
        #pragma unroll
        for (int c = 0; c < 8; c++) s[c] = 0.f;
        #pragma unroll
        for (int it = 0; it < 4; it++) {
            int pt = pbase + it * 8 + hw;
            int j = idx[pt * KK + cl];
            const float* rr = &R[((size_t)(b * NN) + j) * 8];
            float4 ra = *(const float4*)rr;
            float4 rb = *(const float4*)(rr + 4);
            s[0] += ra.x; s[1] += ra.y; s[2] += ra.z; s[3] += ra.w;
            s[4] += rb.x; s[5] += rb.y; s[6] += rb.z; s[7] += rb.w;
        }
        #pragma unroll
        for (int off = 16; off; off >>= 1) {
            #pragma unroll
            for (int c = 0; c < 8; c++) s[c] += __shfl_down(s[c], off, 32);
        }
        if (cl == 0) {
            #pragma unroll
            for (int c = 0; c < 8; c++) sAcc[hw][c] = s[c];
        }
        __syncthreads();
        if (t < 8) {
            float v = 0.f;
            #pragma unroll
            for (int k = 0; k < 8; k++) v += sAcc[k][t];
            Gp[bid * 8 + t] = v;
        }
    }
}

// ---------------- mlp2: grid 512 (2 blocks/CU), 4 cols/wave; XCD batch split -----------
__global__ __launch_bounds__(256, 4)
void k_mlp2(const __half* __restrict__ pselH, const float* __restrict__ Gp,
            const float* __restrict__ w2, const float* __restrict__ b2,
            const float* __restrict__ gd, const float* __restrict__ bed,
            float* __restrict__ oraw, float* __restrict__ Op) {
    __shared__ float w2s[64 * 257];
    __shared__ float sw[4][8];
    __shared__ float sA[4][4], sB[4][4];

    int t = threadIdx.x;
    int w = t >> 6, l = t & 63;
    int q = blockIdx.x;
    int b = ((q & 7) < 4) ? 0 : 1;
    int local = (q >> 3) * 4 + (q & 3);        // [0, 256), unique per batch
    int n0 = local * 16 + w * 4;

    #pragma unroll
    for (int p = 0; p < 16; p++) {
        int i = p * 256 + t;
        int c = i >> 6, mq = i & 63;
        float4 v = ((const float4*)w2)[i];
        float* dst = &w2s[c * 257 + mq * 4];
        dst[0] = v.x; dst[1] = v.y; dst[2] = v.z; dst[3] = v.w;
    }

    {
        float s[8] = {0.f, 0.f, 0.f, 0.f, 0.f, 0.f, 0.f, 0.f};
        if (t < 128) {
            const float4* gp = (const float4*)(Gp + ((size_t)(b * 128 + t)) * 8);
            float4 ra = gp[0], rb = gp[1];
            s[0] = ra.x; s[1] = ra.y; s[2] = ra.z; s[3] = ra.w;
            s[4] = rb.x; s[5] = rb.y; s[6] = rb.z; s[7] = rb.w;
        }
        #pragma unroll
        for (int off = 32; off; off >>= 1) {
            #pragma unroll
            for (int c = 0; c < 8; c++) s[c] += __shfl_down(s[c], off, 64);
        }
        if (l == 0) {
            #pragma unroll
            for (int c = 0; c < 8; c++) sw[w][c] = s[c];
        }
    }
    __syncthreads();

    int g = l >> 4;
    double s1 = (double)sw[0][g] + sw[1][g] + sw[2][g] + sw[3][g];
    double s2 = (double)sw[0][4 + g] + sw[1][4 + g] + sw[2][4 + g] + sw[3][4 + g];
    const double cnt2 = 64.0 * 4096.0 * 32.0;
    double m_ = s1 / cnt2;
    double v_ = s2 / cnt2 - m_ * m_;
    float mean = (float)m_;
    float rstd = rsqrtf((float)v_ + EPSF);
    float4 gd4  = ((const float4*)gd)[l];
    float4 bed4 = ((const float4*)bed)[l];
    float ax = rstd * gd4.x, ay = rstd * gd4.y, az = rstd * gd4.z, aw = rstd * gd4.w;
    float cx = bed4.x - mean * ax, cy = bed4.y - mean * ay;
    float cz = bed4.z - mean * az, cw = bed4.w - mean * aw;

    float4 h2r[4];
    #pragma unroll
    for (int j = 0; j < 4; j++) {
        uint2 raw = *(const uint2*)((const char*)pselH +
                     ((((size_t)(b * NN)) + n0 + j) << 9) + l * 8);
        float2 fa = __half22float2(*(__half2*)&raw.x);
        float2 fb = __half22float2(*(__half2*)&raw.y);
        h2r[j].x = gelu_exact(fmaf(fa.x, ax, cx));
        h2r[j].y = gelu_exact(fmaf(fa.y, ay, cy));
        h2r[j].z = gelu_exact(fmaf(fb.x, az, cz));
        h2r[j].w = gelu_exact(fmaf(fb.y, aw, cw));
    }

    const float* w2l = &w2s[l * 257];
    float acc[4] = {0.f, 0.f, 0.f, 0.f};
    #pragma unroll 8
    for (int mq = 0; mq < 64; mq++) {
        float w0  = w2l[4 * mq + 0];
        float w1_ = w2l[4 * mq + 1];
        float w2_ = w2l[4 * mq + 2];
        float w3_ = w2l[4 * mq + 3];
        #pragma unroll
        for (int j = 0; j < 4; j++) {
            acc[j] = fmaf(w0,  bcast_lane(h2r[j].x, mq), acc[j]);
            acc[j] = fmaf(w1_, bcast_lane(h2r[j].y, mq), acc[j]);
            acc[j] = fmaf(w2_, bcast_lane(h2r[j].z, mq), acc[j]);
            acc[j] = fmaf(w3_, bcast_lane(h2r[j].w, mq), acc[j]);
        }
    }

    float bias = b2[l];
    float so1 = 0.f, so2 = 0.f;
    #pragma unroll
    for (int j = 0; j < 4; j++) {
        acc[j] += bias;
        so1 += acc[j];
        so2 = fmaf(acc[j], acc[j], so2);
    }
    *(float4*)&oraw[((size_t)(b * CC) + l) * NN + n0] =
        make_float4(acc[0], acc[1], acc[2], acc[3]);

    so1 += __shfl_down(so1, 8, 16); so2 += __shfl_down(so2, 8, 16);
    so1 += __shfl_down(so1, 4, 16); so2 += __shfl_down(so2, 4, 16);
    so1 += __shfl_down(so1, 2, 16); so2 += __shfl_down(so2, 2, 16);
    so1 += __shfl_down(so1, 1, 16); so2 += __shfl_down(so2, 1, 16);
    if ((l & 15) == 0) { sA[w][l >> 4] = so1; sB[w][l >> 4] = so2; }
    __syncthreads();
    if (t < 8) {
        int is2 = t >> 2, gg = t & 3;
        float v = is2 ? (sB[0][gg] + sB[1][gg] + sB[2][gg] + sB[3][gg])
                      : (sA[0][gg] + sA[1][gg] + sA[2][gg] + sA[3][gg]);
        Op[(b * 256 + local) * 8 + t] = v;   // {s1 g0..3, s2 g0..3}; 256 rows per batch
    }
}

// ---------------- final: st3 from Op (256 rows/batch), gn3 + residual (float4) ----------
// grid 512, block 256
__global__ void k_final(const float* __restrict__ oraw, const float* __restrict__ x,
                        const float* __restrict__ g2, const float* __restrict__ be2,
                        const float* __restrict__ Op, float* __restrict__ out) {
    __shared__ float fw[4][8];
    int t = threadIdx.x;
    int i4 = blockIdx.x * 256 + t;
    int base = i4 * 4;
    int b = base >> 18;

    {
        const float4* rp = (const float4*)(Op + ((size_t)(b * 256 + t)) * 8);
        float4 ra = rp[0], rb = rp[1];
        float s[8] = {ra.x, ra.y, ra.z, ra.w, rb.x, rb.y, rb.z, rb.w};
        #pragma unroll
        for (int off = 32; off; off >>= 1) {
            #pragma unroll
            for (int c = 0; c < 8; c++) s[c] += __shfl_down(s[c], off, 64);
        }
        if ((t & 63) == 0) {
            #pragma unroll
            for (int c = 0; c < 8; c++) fw[t >> 6][c] = s[c];
        }
    }
    __syncthreads();

    int c = (base >> 12) & 63;
    int g = c >> 4;
    double s1 = (double)fw[0][g] + fw[1][g] + fw[2][g] + fw[3][g];
    double s2 = (double)fw[0][4 + g] + fw[1][4 + g] + fw[2][4 + g] + fw[3][4 + g];
    const double cnt = 16.0 * 4096.0;
    double mean_d = s1 / cnt;
    double var_d  = s2 / cnt - mean_d * mean_d;
    float mean = (float)mean_d;
    float rstd = rsqrtf((float)var_d + EPSF);
    float sc = rstd * g2[c];
    float ad = be2[c] - mean * sc;
    float4 o = ((const float4*)oraw)[i4];
    float4 xv = ((const float4*)x)[i4];
    float4 r;
    r.x = fmaf(o.x, sc, ad) + xv.x;
    r.y = fmaf(o.y, sc, ad) + xv.y;
    r.z = fmaf(o.z, sc, ad) + xv.z;
    r.w = fmaf(o.w, sc, ad) + xv.w;
    ((float4*)out)[i4] = r;
}

// ---------------- launch ----------------
extern "C" void kernel_launch(void* const* d_in, const int* in_sizes, int n_in,
                              void* d_out, int out_size, void* d_ws, size_t ws_size,
                              hipStream_t stream) {
    const float* x   = (const float*)d_in[0];
    const float* pos = (const float*)d_in[1];
    const float* w1  = (const float*)d_in[2];
    const float* b1  = (const float*)d_in[3];
    const float* g1  = (const float*)d_in[4];
    const float* be1 = (const float*)d_in[5];
    const float* wd  = (const float*)d_in[6];
    const float* gd  = (const float*)d_in[7];
    const float* bed = (const float*)d_in[8];
    const float* w2  = (const float*)d_in[9];
    const float* b2  = (const float*)d_in[10];
    const float* g2  = (const float*)d_in[11];
    const float* be2 = (const float*)d_in[12];
    float* out = (float*)d_out;

    char* wsb = (char*)d_ws;
    __half* hH    = (__half*)wsb;                    // 4 MB (fp16 h)
    __half* pH    = (__half*)(wsb + 8388608);        // 4 MB
    __half* pselH = (__half*)(wsb + 12582912);       // 4 MB
    float*  oraw  = (float*)(wsb + 16777216);        // 2 MB
    int*    idx   = (int*)(wsb + 18874368);          // 1 MB
    float*  R     = (float*)(wsb + 19922944);        // 256 KB
    float2* Mp    = (float2*)(wsb + 20185088);       // 4 KB
    float*  Gp    = (float*)(wsb + 20189184);        // 8 KB
    float*  Op    = (float*)(wsb + 20197376);        // 16 KB

    k_mlp1<<<512, 256, 0, stream>>>(x, w1, b1, hH, Mp);
    k_gn1t_ballq<<<2560, 256, 0, stream>>>(hH, g1, be1, wd, Mp, pH, R, pos, idx);
    k_qgather_gstats<<<2304, 256, 0, stream>>>(pH, idx, R, gd, pselH, Gp);
    k_mlp2<<<512, 256, 0, stream>>>(pselH, Gp, w2, b2, gd, bed, oraw, Op);
    k_final<<<512, 256, 0, stream>>>(oraw, x, g2, be2, Op, out);
}